// Round 1
// 4498.628 us; speedup vs baseline: 1.3834x; 1.3834x over previous
//
#include <hip/hip_runtime.h>
#include <hip/hip_bf16.h>

// ViT-B/16 forward, MI355X. Round 3: MFMA fused attention (16x16x32 bf16),
// in-register softmax, LDS-aliased P buffer, XOR-swizzled V^T.
// GEMMs unchanged from round 2 (128x128 tile, BK=32).
//
// B=32, IMG=224 -> 196 patches +cls = 197 tokens, DIM=768, HEADS=12, HD=64,
// FF=3072, DEPTH=12, NRD=732.

#define B_     32
#define DIM_   768
#define N_     197
#define M_     (B_*N_)      // 6304
#define NP_    196
#define MP_    (B_*NP_)     // 6272
#define HEADS_ 12
#define HD_    64
#define FF_    3072
#define NRD_   732
#define QKV_   2304

typedef unsigned short u16;
typedef unsigned int   u32;
typedef __attribute__((ext_vector_type(4))) float    f32x4;
typedef __attribute__((ext_vector_type(8))) u16      ushort8;
typedef __attribute__((ext_vector_type(8))) __bf16   bf16x8;

__device__ __forceinline__ float b2f(u16 u) {
    return __builtin_bit_cast(float, ((u32)u) << 16);
}
__device__ __forceinline__ u16 f2b(float f) {  // RNE f32->bf16
    u32 u = __builtin_bit_cast(u32, f);
    u32 r = u + 0x7fffu + ((u >> 16) & 1u);
    return (u16)(r >> 16);
}
__device__ __forceinline__ float lo16(u32 v) { return __builtin_bit_cast(float, v << 16); }
__device__ __forceinline__ float hi16(u32 v) { return __builtin_bit_cast(float, v & 0xffff0000u); }

__device__ __forceinline__ f32x4 mfma16(ushort8 a, ushort8 b, f32x4 c) {
    return __builtin_amdgcn_mfma_f32_16x16x32_bf16(
        __builtin_bit_cast(bf16x8, a), __builtin_bit_cast(bf16x8, b), c, 0, 0, 0);
}

// ---------------- f32 -> bf16 converters ----------------
__global__ void cvt_k(const float* __restrict__ src, u16* __restrict__ dst, int n8) {
    int g = blockIdx.x * 256 + threadIdx.x;
    if (g >= n8) return;
    size_t o = (size_t)g * 8;
    float4 f0 = *(const float4*)(src + o);
    float4 f1 = *(const float4*)(src + o + 4);
    ushort8 r;
    r[0]=f2b(f0.x); r[1]=f2b(f0.y); r[2]=f2b(f0.z); r[3]=f2b(f0.w);
    r[4]=f2b(f1.x); r[5]=f2b(f1.y); r[6]=f2b(f1.z); r[7]=f2b(f1.w);
    *(ushort8*)(dst + o) = r;
}

// one layer's 4 weight mats -> contiguous bf16 wbuf [qkv|proj|fc1|fc2]
#define SEG0 1769472   // 2304*768
#define SEG1 589824    // 768*768
#define SEG2 2359296   // 3072*768
#define SEG3 2359296   // 768*3072
__global__ void cvt4_k(const float* __restrict__ s0, const float* __restrict__ s1,
                       const float* __restrict__ s2, const float* __restrict__ s3,
                       u16* __restrict__ dst) {
    int g = blockIdx.x * 256 + threadIdx.x;
    if (g >= (SEG0+SEG1+SEG2+SEG3)/8) return;
    size_t o = (size_t)g * 8;
    const float* src; size_t lo_;
    if (o < SEG0)             { src = s0; lo_ = o; }
    else if (o < SEG0+SEG1)   { src = s1; lo_ = o - SEG0; }
    else if (o < (size_t)SEG0+SEG1+SEG2) { src = s2; lo_ = o - SEG0 - SEG1; }
    else                      { src = s3; lo_ = o - SEG0 - SEG1 - SEG2; }
    float4 f0 = *(const float4*)(src + lo_);
    float4 f1 = *(const float4*)(src + lo_ + 4);
    ushort8 r;
    r[0]=f2b(f0.x); r[1]=f2b(f0.y); r[2]=f2b(f0.z); r[3]=f2b(f0.w);
    r[4]=f2b(f1.x); r[5]=f2b(f1.y); r[6]=f2b(f1.z); r[7]=f2b(f1.w);
    *(ushort8*)(dst + o) = r;
}

// ---------------- patchify: x[B,3,224,224] -> P bf16 [6272,768]
__global__ void patchify_k(const float* __restrict__ X, u16* __restrict__ P) {
    int idx = blockIdx.x * 256 + threadIdx.x;
    if (idx >= MP_ * DIM_) return;
    int row = idx / DIM_, k = idx - row * DIM_;
    int b = row / NP_, p = row - b * NP_;
    int gy = p / 14, gx = p - gy * 14;
    int c = k >> 8, r = k & 255;
    int py = r >> 4, px = r & 15;
    P[idx] = f2b(X[((b * 3 + c) * 224 + gy * 16 + py) * 224 + gx * 16 + px]);
}

// ---------------- tokens: f32 patch-GEMM out + cls -> h f32
__global__ void build_tokens_k(const float* __restrict__ P, const float* __restrict__ cls,
                               float* __restrict__ T) {
    int idx = blockIdx.x * 256 + threadIdx.x;
    if (idx >= M_ * DIM_) return;
    int row = idx / DIM_, c = idx - row * DIM_;
    int b = row / N_, t = row - b * N_;
    T[idx] = (t == 0) ? cls[c] : P[(size_t)(b * NP_ + t - 1) * DIM_ + c];
}

// ---------------- qkv bias = concat(q_bias, 0, v_bias)  (f32)
__global__ void qkvbias_k(const float* __restrict__ qb, const float* __restrict__ vb,
                          float* __restrict__ out) {
    int n = blockIdx.x * 256 + threadIdx.x;
    if (n >= QKV_) return;
    out[n] = (n < DIM_) ? qb[n] : (n < 2 * DIM_ ? 0.f : vb[n - 2 * DIM_]);
}

// ---------------- LayerNorm (biased var, eps=1e-5). One block(256) per row.
template <int OUTBF>
__global__ void layernorm_k(const float* __restrict__ X, const float* __restrict__ w,
                            const float* __restrict__ bta, void* __restrict__ Yv) {
    int row = blockIdx.x;
    const float* x = X + (size_t)row * DIM_;
    int t = threadIdx.x;
    float v[3]; float s = 0.f, q = 0.f;
#pragma unroll
    for (int i = 0; i < 3; i++) { float u = x[t + i * 256]; v[i] = u; s += u; q += u * u; }
#pragma unroll
    for (int off = 32; off > 0; off >>= 1) {
        s += __shfl_down(s, off, 64);
        q += __shfl_down(q, off, 64);
    }
    __shared__ float ss[4], qq[4];
    int wid = t >> 6, lane = t & 63;
    if (!lane) { ss[wid] = s; qq[wid] = q; }
    __syncthreads();
    s = ss[0] + ss[1] + ss[2] + ss[3];
    q = qq[0] + qq[1] + qq[2] + qq[3];
    float mu = s * (1.f / 768.f);
    float var = q * (1.f / 768.f) - mu * mu;
    float rs = rsqrtf(var + 1e-5f);
#pragma unroll
    for (int i = 0; i < 3; i++) {
        int c = t + i * 256;
        float o = (v[i] - mu) * rs * w[c] + bta[c];
        if (OUTBF) ((u16*)Yv)[(size_t)row * DIM_ + c] = f2b(o);
        else       ((float*)Yv)[(size_t)row * DIM_ + c] = o;
    }
}

// ---------------- MFMA NT GEMM: C[M,Nc] = A[M,K](bf16) * W[Nc,K]^T(bf16)
// 128x128 tile, BK=32, 4 waves each 64x64 (4x4 of 16x16x32 mfma).
// Nc % 128 == 0; M edge clamped on load, masked on store.
template <int ACT, int OUTBF>   // ACT: erf-GELU; OUTBF: store bf16 else f32
__launch_bounds__(256)
__global__ void gemm_bt(const u16* __restrict__ A, const u16* __restrict__ W,
                        const float* __restrict__ bias, const float* res,
                        void* Cv, int M, int Nc, int K) {
    __shared__ u16 As[128 * 32];
    __shared__ u16 Ws[128 * 32];
    const int tid = threadIdx.x;
    const int lane = tid & 63, w = tid >> 6;
    const int wm = w & 1, wn = w >> 1;
    const int m0 = blockIdx.y * 128, n0 = blockIdx.x * 128;
    const int r0 = tid >> 2, sg = (tid & 3) * 8;  // staging: 16B per thread, 2 passes
    f32x4 acc[4][4] = {};
    for (int k0 = 0; k0 < K; k0 += 32) {
        int ar0 = m0 + r0;      if (ar0 >= M) ar0 = M - 1;
        int ar1 = m0 + r0 + 64; if (ar1 >= M) ar1 = M - 1;
        ushort8 a0 = *(const ushort8*)(A + (size_t)ar0 * K + k0 + sg);
        ushort8 a1 = *(const ushort8*)(A + (size_t)ar1 * K + k0 + sg);
        ushort8 w0 = *(const ushort8*)(W + (size_t)(n0 + r0) * K + k0 + sg);
        ushort8 w1 = *(const ushort8*)(W + (size_t)(n0 + r0 + 64) * K + k0 + sg);
        __syncthreads();   // previous iteration's fragment reads done
        *(ushort8*)(As + r0 * 32 + sg) = a0;
        *(ushort8*)(As + (r0 + 64) * 32 + sg) = a1;
        *(ushort8*)(Ws + r0 * 32 + sg) = w0;
        *(ushort8*)(Ws + (r0 + 64) * 32 + sg) = w1;
        __syncthreads();
        ushort8 af[4], bfr[4];
#pragma unroll
        for (int mi = 0; mi < 4; mi++)
            af[mi] = *(const ushort8*)(As + (wm * 64 + mi * 16 + (lane & 15)) * 32 + (lane >> 4) * 8);
#pragma unroll
        for (int ni = 0; ni < 4; ni++)
            bfr[ni] = *(const ushort8*)(Ws + (wn * 64 + ni * 16 + (lane & 15)) * 32 + (lane >> 4) * 8);
#pragma unroll
        for (int mi = 0; mi < 4; mi++)
#pragma unroll
            for (int ni = 0; ni < 4; ni++)
                acc[mi][ni] = mfma16(af[mi], bfr[ni], acc[mi][ni]);
    }
    // epilogue: D(row,col): row = quad*4+reg, col = lane&15 (m89-verified layout)
    const int cb = n0 + wn * 64 + (lane & 15);
    const int rb = m0 + wm * 64 + ((lane >> 4) * 4);
#pragma unroll
    for (int ni = 0; ni < 4; ni++) {
        int col = cb + ni * 16;
        float bv = bias ? bias[col] : 0.f;
#pragma unroll
        for (int mi = 0; mi < 4; mi++) {
#pragma unroll
            for (int rg = 0; rg < 4; rg++) {
                int row = rb + mi * 16 + rg;
                if (row >= M) continue;
                float t = acc[mi][ni][rg] + bv;
                if (ACT) t = 0.5f * t * (1.f + erff(t * 0.70710678118654752f));
                if (res) t += res[(size_t)row * Nc + col];
                if (OUTBF) ((u16*)Cv)[(size_t)row * Nc + col] = f2b(t);
                else       ((float*)Cv)[(size_t)row * Nc + col] = t;
            }
        }
    }
}

// ---------------- fused MFMA attention.
// qkv bf16 [M,2304] (q|k|v); rpt f32 [NRD,12]; O bf16 [M,768].
// grid (384, 4): block = (b,h) x 64 q-rows. 4 waves, wave w owns rows
// iw = y*64 + w*16 .. +15 (16x16x32 MFMA tiles). N padded to 224 (14 col
// tiles / 7 PV k-steps).
// LDS: Ks [224][72] bf16 (stride-72 -> conflict-free b128 B-frag reads),
//      Vt [64][256] bf16 XOR-swizzled (j ^= ((d&7)^((d>>3)&7))<<3) so both
//      the scalar transpose writes and the b128 B-frag reads are bank-free.
// Ps [64][232] ALIASES Ks (dead after the QK^T barrier) -> 63.5 KB total,
// 2 blocks/CU.
__device__ __forceinline__ int vswz(int d) {
    return ((d & 7) ^ ((d >> 3) & 7)) << 3;
}

__launch_bounds__(256)
__global__ void attn3_k(const u16* __restrict__ qkv, const float* __restrict__ rpt,
                        u16* __restrict__ O) {
    __shared__ u16 smem[16128 + 16384];          // 63.5 KB
    u16* Ks = smem;                              // [224][72]
    u16* Vt = smem + 16128;                      // [64][256] swizzled
    u16* Ps = smem;                              // [64][232], aliases Ks
    const int b = blockIdx.x / HEADS_, hh = blockIdx.x % HEADS_;
    const int i0 = blockIdx.y * 64;
    const int t = threadIdx.x;
    const int w = t >> 6, lane = t & 63;
    const int lhi = lane >> 4, llo = lane & 15;
    const size_t base = (size_t)b * N_ * QKV_ + (size_t)hh * HD_;
    const int iw = i0 + w * 16;

    // Q A-fragments straight from global (A[m=llo][k=lhi*8+e], kk=0,1)
    int qrow = iw + llo; if (qrow > 196) qrow = 196;
    const ushort8 af0 = *(const ushort8*)(qkv + base + (size_t)qrow * QKV_ + lhi * 8);
    const ushort8 af1 = *(const ushort8*)(qkv + base + (size_t)qrow * QKV_ + 32 + lhi * 8);

    // stage K rows + swizzled V^T
    for (int g = t; g < 1576; g += 256) {
        int j = g >> 3, d0 = (g & 7) * 8;
        ushort8 kv = *(const ushort8*)(qkv + base + (size_t)j * QKV_ + 768 + d0);
        *(ushort8*)(Ks + j * 72 + d0) = kv;
        ushort8 vv = *(const ushort8*)(qkv + base + (size_t)j * QKV_ + 1536 + d0);
#pragma unroll
        for (int e = 0; e < 8; e++) {
            int d = d0 + e;
            Vt[d * 256 + (j ^ vswz(d))] = ((const u16*)&vv)[e];
        }
    }
    // zero pads: Ks rows 197..223, Vt logical cols 197..223
    if (t < 216) {
        int j = 197 + (t >> 3), d0 = (t & 7) * 8;
        *(uint4*)(Ks + j * 72 + d0) = make_uint4(0u, 0u, 0u, 0u);
    }
    for (int g = t; g < 1728; g += 256) {
        int d = g / 27, c = 197 + (g - d * 27);
        Vt[d * 256 + (c ^ vswz(d))] = 0;
    }
    __syncthreads();

    const bool wvalid = (iw <= 196);
    f32x4 acc[14] = {};
    float mx[4], sum[4];

    if (wvalid) {
        // ---- QK^T: S[iw+0..15][0..223]
#pragma unroll
        for (int jt = 0; jt < 14; jt++) {
            const u16* kp = Ks + (jt * 16 + llo) * 72 + lhi * 8;
            ushort8 b0 = *(const ushort8*)(kp);
            ushort8 b1 = *(const ushort8*)(kp + 32);
            acc[jt] = mfma16(af0, b0, acc[jt]);
            acc[jt] = mfma16(af1, b1, acc[jt]);
        }
        // ---- bias + mask + row max (rows live in 16 lanes differing in bits 0-3)
        int iy4[4], ix4[4]; bool icls[4];
#pragma unroll
        for (int rg = 0; rg < 4; rg++) {
            int i = iw + lhi * 4 + rg; if (i > 196) i = 196;
            icls[rg] = (i == 0);
            int pi = i - 1;
            iy4[rg] = pi / 14; ix4[rg] = pi - iy4[rg] * 14;
            mx[rg] = -INFINITY;
        }
#pragma unroll
        for (int jt = 0; jt < 14; jt++) {
            int j = jt * 16 + llo;
            if (j <= 196) {
                bool jcls = (j == 0);
                int pj = j - 1;
                int jy = pj / 14, jx = pj - jy * 14;
#pragma unroll
                for (int rg = 0; rg < 4; rg++) {
                    int idx;
                    if (icls[rg])  idx = jcls ? (NRD_ - 1) : (NRD_ - 3);
                    else if (jcls) idx = NRD_ - 2;
                    else           idx = (iy4[rg] - jy + 13) * 27 + (ix4[rg] - jx + 13);
                    float sv = acc[jt][rg] * 0.125f + rpt[idx * HEADS_ + hh];
                    acc[jt][rg] = sv;
                    mx[rg] = fmaxf(mx[rg], sv);
                }
            } else {
#pragma unroll
                for (int rg = 0; rg < 4; rg++) acc[jt][rg] = -INFINITY;
            }
        }
#pragma unroll
        for (int rg = 0; rg < 4; rg++) {
#pragma unroll
            for (int off = 1; off < 16; off <<= 1)
                mx[rg] = fmaxf(mx[rg], __shfl_xor(mx[rg], off, 64));
            sum[rg] = 0.f;
        }
        // ---- exp + row sum + normalize (in registers)
#pragma unroll
        for (int jt = 0; jt < 14; jt++)
#pragma unroll
            for (int rg = 0; rg < 4; rg++) {
                float ev = __expf(acc[jt][rg] - mx[rg]);
                acc[jt][rg] = ev;
                sum[rg] += ev;
            }
#pragma unroll
        for (int rg = 0; rg < 4; rg++) {
#pragma unroll
            for (int off = 1; off < 16; off <<= 1)
                sum[rg] += __shfl_xor(sum[rg], off, 64);
            sum[rg] = 1.f / sum[rg];
        }
#pragma unroll
        for (int jt = 0; jt < 14; jt++)
#pragma unroll
            for (int rg = 0; rg < 4; rg++) acc[jt][rg] *= sum[rg];
    }
    __syncthreads();   // all Ks reads done -> Ps may overwrite

    if (wvalid) {
        // ---- write P (bf16) to own 16 rows of Ps
#pragma unroll
        for (int jt = 0; jt < 14; jt++)
#pragma unroll
            for (int rg = 0; rg < 4; rg++)
                Ps[(w * 16 + lhi * 4 + rg) * 232 + jt * 16 + llo] = f2b(acc[jt][rg]);
        // ---- PV: O[16 x 64] = P[16 x 224] @ V[224 x 64]
        f32x4 o[4] = {};
#pragma unroll
        for (int jk = 0; jk < 7; jk++) {
            ushort8 pa = *(const ushort8*)(Ps + (w * 16 + llo) * 232 + jk * 32 + lhi * 8);
#pragma unroll
            for (int dt = 0; dt < 4; dt++) {
                int d = dt * 16 + llo;
                ushort8 vf = *(const ushort8*)(Vt + d * 256 + ((jk * 32 + lhi * 8) ^ vswz(d)));
                o[dt] = mfma16(pa, vf, o[dt]);
            }
        }
        // ---- store (row = lhi*4+rg, col = dt*16+llo)
#pragma unroll
        for (int dt = 0; dt < 4; dt++)
#pragma unroll
            for (int rg = 0; rg < 4; rg++) {
                int i = iw + lhi * 4 + rg;
                if (i <= 196)
                    O[(size_t)(b * N_ + i) * DIM_ + hh * HD_ + dt * 16 + llo] = f2b(o[dt][rg]);
            }
    }
}

extern "C" void kernel_launch(void* const* d_in, const int* in_sizes, int n_in,
                              void* d_out, int out_size, void* d_ws, size_t ws_size,
                              hipStream_t stream) {
    (void)in_sizes; (void)n_in; (void)out_size; (void)ws_size;
    const float* x    = (const float*)d_in[0];
    const float* pew  = (const float*)d_in[1];
    const float* peb  = (const float*)d_in[2];
    const float* cls  = (const float*)d_in[3];
    const float* n1w  = (const float*)d_in[4];
    const float* n1b  = (const float*)d_in[5];
    const float* qkvw = (const float*)d_in[6];
    const float* qb   = (const float*)d_in[7];
    const float* vb   = (const float*)d_in[8];
    const float* rpt  = (const float*)d_in[9];
    const float* pw   = (const float*)d_in[10];
    const float* pb   = (const float*)d_in[11];
    const float* n2w  = (const float*)d_in[12];
    const float* n2b  = (const float*)d_in[13];
    const float* f1w  = (const float*)d_in[14];
    const float* f1b  = (const float*)d_in[15];
    const float* f2w  = (const float*)d_in[16];
    const float* f2b_ = (const float*)d_in[17];
    const float* nfw  = (const float*)d_in[18];
    const float* nfb  = (const float*)d_in[19];

    // workspace (floats): h | y(bf16) | un | wbuf(bf16) | qbias  ~= 82 MB
    float* ws = (float*)d_ws;
    float* h     = ws;                                   // 4,841,472 f32
    u16*   y     = (u16*)(ws + 4841472);                 // bf16 [M,768]
    float* un    = ws + 4841472 + 2420736;               // 9,682,944 f32 union
    u16*   wbuf  = (u16*)(un + 9682944);                 // 7,077,888 bf16
    float* qbias = (float*)(wbuf + 7077888);             // 2304 f32
    u16*   qkvb   = (u16*)un;                            // bf16 [M,2304]
    u16*   hidden = (u16*)un;                            // bf16 [M,3072]
    u16*   pmat   = (u16*)un;                            // bf16 [6272,768]
    float* pout   = un + 4816896;                        // f32  [6272,768]

    const int MT = (M_ + 127) / 128;  // 50

    // patch embed
    cvt_k<<<288, 256, 0, stream>>>(pew, wbuf, SEG1 / 8);
    patchify_k<<<(MP_ * DIM_ + 255) / 256, 256, 0, stream>>>(x, pmat);
    gemm_bt<0, 0><<<dim3(6, 49), 256, 0, stream>>>(pmat, wbuf, peb, nullptr, pout,
                                                   MP_, DIM_, DIM_);
    build_tokens_k<<<(M_ * DIM_ + 255) / 256, 256, 0, stream>>>(pout, cls, h);

    for (int l = 0; l < 12; l++) {
        layernorm_k<1><<<M_, 256, 0, stream>>>(h, n1w + l * DIM_, n1b + l * DIM_, y);
        cvt4_k<<<3456, 256, 0, stream>>>(qkvw + (size_t)l * SEG0, pw + (size_t)l * SEG1,
                                         f1w + (size_t)l * SEG2, f2w + (size_t)l * SEG3, wbuf);
        qkvbias_k<<<9, 256, 0, stream>>>(qb + l * DIM_, vb + l * DIM_, qbias);
        gemm_bt<0, 1><<<dim3(18, MT), 256, 0, stream>>>(y, wbuf, qbias, nullptr, qkvb,
                                                        M_, QKV_, DIM_);
        attn3_k<<<dim3(384, 4), 256, 0, stream>>>(qkvb, rpt + (size_t)l * NRD_ * HEADS_, y);
        gemm_bt<0, 0><<<dim3(6, MT), 256, 0, stream>>>(y, wbuf + SEG0, pb + l * DIM_, h, h,
                                                       M_, DIM_, DIM_);
        layernorm_k<1><<<M_, 256, 0, stream>>>(h, n2w + l * DIM_, n2b + l * DIM_, y);
        gemm_bt<1, 1><<<dim3(24, MT), 256, 0, stream>>>(y, wbuf + SEG0 + SEG1, f1b + l * FF_,
                                                        nullptr, hidden, M_, FF_, DIM_);
        gemm_bt<0, 0><<<dim3(6, MT), 256, 0, stream>>>(hidden, wbuf + SEG0 + SEG1 + SEG2,
                                                       f2b_ + l * DIM_, h, h, M_, DIM_, FF_);
    }
    layernorm_k<0><<<M_, 256, 0, stream>>>(h, nfw, nfb, d_out);
}

// Round 2
// 4474.136 us; speedup vs baseline: 1.3910x; 1.0055x over previous
//
#include <hip/hip_runtime.h>
#include <hip/hip_bf16.h>

// ViT-B/16 forward, MI355X. Round 4: GEMM staging via global_load_lds
// (width-16 async global->LDS, m97 structure). MFMA attention unchanged.
//
// B=32, IMG=224 -> 196 patches +cls = 197 tokens, DIM=768, HEADS=12, HD=64,
// FF=3072, DEPTH=12, NRD=732.

#define B_     32
#define DIM_   768
#define N_     197
#define M_     (B_*N_)      // 6304
#define NP_    196
#define MP_    (B_*NP_)     // 6272
#define HEADS_ 12
#define HD_    64
#define FF_    3072
#define NRD_   732
#define QKV_   2304

typedef unsigned short u16;
typedef unsigned int   u32;
typedef __attribute__((ext_vector_type(4))) float    f32x4;
typedef __attribute__((ext_vector_type(8))) u16      ushort8;
typedef __attribute__((ext_vector_type(8))) __bf16   bf16x8;

__device__ __forceinline__ float b2f(u16 u) {
    return __builtin_bit_cast(float, ((u32)u) << 16);
}
__device__ __forceinline__ u16 f2b(float f) {  // RNE f32->bf16
    u32 u = __builtin_bit_cast(u32, f);
    u32 r = u + 0x7fffu + ((u >> 16) & 1u);
    return (u16)(r >> 16);
}
__device__ __forceinline__ float lo16(u32 v) { return __builtin_bit_cast(float, v << 16); }
__device__ __forceinline__ float hi16(u32 v) { return __builtin_bit_cast(float, v & 0xffff0000u); }

__device__ __forceinline__ f32x4 mfma16(ushort8 a, ushort8 b, f32x4 c) {
    return __builtin_amdgcn_mfma_f32_16x16x32_bf16(
        __builtin_bit_cast(bf16x8, a), __builtin_bit_cast(bf16x8, b), c, 0, 0, 0);
}

// async 16B global->LDS copy: lds base must be wave-uniform; g is per-lane.
__device__ __forceinline__ void gload16(const u16* g, u16* lds) {
    __builtin_amdgcn_global_load_lds(
        (const __attribute__((address_space(1))) void*)g,
        (__attribute__((address_space(3))) void*)lds, 16, 0, 0);
}

// ---------------- f32 -> bf16 converters ----------------
__global__ void cvt_k(const float* __restrict__ src, u16* __restrict__ dst, int n8) {
    int g = blockIdx.x * 256 + threadIdx.x;
    if (g >= n8) return;
    size_t o = (size_t)g * 8;
    float4 f0 = *(const float4*)(src + o);
    float4 f1 = *(const float4*)(src + o + 4);
    ushort8 r;
    r[0]=f2b(f0.x); r[1]=f2b(f0.y); r[2]=f2b(f0.z); r[3]=f2b(f0.w);
    r[4]=f2b(f1.x); r[5]=f2b(f1.y); r[6]=f2b(f1.z); r[7]=f2b(f1.w);
    *(ushort8*)(dst + o) = r;
}

// one layer's 4 weight mats -> contiguous bf16 wbuf [qkv|proj|fc1|fc2]
#define SEG0 1769472   // 2304*768
#define SEG1 589824    // 768*768
#define SEG2 2359296   // 3072*768
#define SEG3 2359296   // 768*3072
__global__ void cvt4_k(const float* __restrict__ s0, const float* __restrict__ s1,
                       const float* __restrict__ s2, const float* __restrict__ s3,
                       u16* __restrict__ dst) {
    int g = blockIdx.x * 256 + threadIdx.x;
    if (g >= (SEG0+SEG1+SEG2+SEG3)/8) return;
    size_t o = (size_t)g * 8;
    const float* src; size_t lo_;
    if (o < SEG0)             { src = s0; lo_ = o; }
    else if (o < SEG0+SEG1)   { src = s1; lo_ = o - SEG0; }
    else if (o < (size_t)SEG0+SEG1+SEG2) { src = s2; lo_ = o - SEG0 - SEG1; }
    else                      { src = s3; lo_ = o - SEG0 - SEG1 - SEG2; }
    float4 f0 = *(const float4*)(src + lo_);
    float4 f1 = *(const float4*)(src + lo_ + 4);
    ushort8 r;
    r[0]=f2b(f0.x); r[1]=f2b(f0.y); r[2]=f2b(f0.z); r[3]=f2b(f0.w);
    r[4]=f2b(f1.x); r[5]=f2b(f1.y); r[6]=f2b(f1.z); r[7]=f2b(f1.w);
    *(ushort8*)(dst + o) = r;
}

// ---------------- patchify: x[B,3,224,224] -> P bf16 [6272,768]
__global__ void patchify_k(const float* __restrict__ X, u16* __restrict__ P) {
    int idx = blockIdx.x * 256 + threadIdx.x;
    if (idx >= MP_ * DIM_) return;
    int row = idx / DIM_, k = idx - row * DIM_;
    int b = row / NP_, p = row - b * NP_;
    int gy = p / 14, gx = p - gy * 14;
    int c = k >> 8, r = k & 255;
    int py = r >> 4, px = r & 15;
    P[idx] = f2b(X[((b * 3 + c) * 224 + gy * 16 + py) * 224 + gx * 16 + px]);
}

// ---------------- tokens: f32 patch-GEMM out + cls -> h f32
__global__ void build_tokens_k(const float* __restrict__ P, const float* __restrict__ cls,
                               float* __restrict__ T) {
    int idx = blockIdx.x * 256 + threadIdx.x;
    if (idx >= M_ * DIM_) return;
    int row = idx / DIM_, c = idx - row * DIM_;
    int b = row / N_, t = row - b * N_;
    T[idx] = (t == 0) ? cls[c] : P[(size_t)(b * NP_ + t - 1) * DIM_ + c];
}

// ---------------- qkv bias = concat(q_bias, 0, v_bias)  (f32)
__global__ void qkvbias_k(const float* __restrict__ qb, const float* __restrict__ vb,
                          float* __restrict__ out) {
    int n = blockIdx.x * 256 + threadIdx.x;
    if (n >= QKV_) return;
    out[n] = (n < DIM_) ? qb[n] : (n < 2 * DIM_ ? 0.f : vb[n - 2 * DIM_]);
}

// ---------------- LayerNorm (biased var, eps=1e-5). One block(256) per row.
template <int OUTBF>
__global__ void layernorm_k(const float* __restrict__ X, const float* __restrict__ w,
                            const float* __restrict__ bta, void* __restrict__ Yv) {
    int row = blockIdx.x;
    const float* x = X + (size_t)row * DIM_;
    int t = threadIdx.x;
    float v[3]; float s = 0.f, q = 0.f;
#pragma unroll
    for (int i = 0; i < 3; i++) { float u = x[t + i * 256]; v[i] = u; s += u; q += u * u; }
#pragma unroll
    for (int off = 32; off > 0; off >>= 1) {
        s += __shfl_down(s, off, 64);
        q += __shfl_down(q, off, 64);
    }
    __shared__ float ss[4], qq[4];
    int wid = t >> 6, lane = t & 63;
    if (!lane) { ss[wid] = s; qq[wid] = q; }
    __syncthreads();
    s = ss[0] + ss[1] + ss[2] + ss[3];
    q = qq[0] + qq[1] + qq[2] + qq[3];
    float mu = s * (1.f / 768.f);
    float var = q * (1.f / 768.f) - mu * mu;
    float rs = rsqrtf(var + 1e-5f);
#pragma unroll
    for (int i = 0; i < 3; i++) {
        int c = t + i * 256;
        float o = (v[i] - mu) * rs * w[c] + bta[c];
        if (OUTBF) ((u16*)Yv)[(size_t)row * DIM_ + c] = f2b(o);
        else       ((float*)Yv)[(size_t)row * DIM_ + c] = o;
    }
}

// ---------------- MFMA NT GEMM: C[M,Nc] = A[M,K](bf16) * W[Nc,K]^T(bf16)
// 128x128 tile, BK=32, 4 waves each 64x64 (4x4 of 16x16x32 mfma).
// Staging: global_load_lds width-16 (m97 structure). Wave w stages 32 rows
// of As and Ws (2 calls each of 16 rows; LDS base wave-uniform, global addr
// per-lane, lane l covers row l>>2, 16B slot l&3).
// Nc % 128 == 0; M edge clamped on load, masked on store.
template <int ACT, int OUTBF>   // ACT: erf-GELU; OUTBF: store bf16 else f32
__launch_bounds__(256)
__global__ void gemm_bt(const u16* __restrict__ A, const u16* __restrict__ W,
                        const float* __restrict__ bias, const float* res,
                        void* Cv, int M, int Nc, int K) {
    __shared__ u16 As[128 * 32];
    __shared__ u16 Ws[128 * 32];
    const int tid = threadIdx.x;
    const int lane = tid & 63, w = tid >> 6;
    const int wm = w & 1, wn = w >> 1;
    const int m0 = blockIdx.y * 128, n0 = blockIdx.x * 128;
    f32x4 acc[4][4] = {};

    // per-lane global staging addresses (hoisted; +k0 per iter)
    const int srow = lane >> 2, scol = (lane & 3) * 8;
    int ar0 = m0 + w * 32 + srow;       if (ar0 >= M) ar0 = M - 1;
    int ar1 = m0 + w * 32 + 16 + srow;  if (ar1 >= M) ar1 = M - 1;
    const u16* ga0 = A + (size_t)ar0 * K + scol;
    const u16* ga1 = A + (size_t)ar1 * K + scol;
    const u16* gw0 = W + (size_t)(n0 + w * 32 + srow) * K + scol;
    const u16* gw1 = W + (size_t)(n0 + w * 32 + 16 + srow) * K + scol;
    // wave-uniform LDS bases (16 rows x 64B = 1KB per call)
    u16* la0 = As + (w * 32) * 32;
    u16* la1 = As + (w * 32 + 16) * 32;
    u16* lw0 = Ws + (w * 32) * 32;
    u16* lw1 = Ws + (w * 32 + 16) * 32;

    for (int k0 = 0; k0 < K; k0 += 32) {
        gload16(ga0 + k0, la0);
        gload16(ga1 + k0, la1);
        gload16(gw0 + k0, lw0);
        gload16(gw1 + k0, lw1);
        __syncthreads();   // drains vmcnt -> staging visible to all waves
        ushort8 af[4], bfr[4];
#pragma unroll
        for (int mi = 0; mi < 4; mi++)
            af[mi] = *(const ushort8*)(As + (wm * 64 + mi * 16 + (lane & 15)) * 32 + (lane >> 4) * 8);
#pragma unroll
        for (int ni = 0; ni < 4; ni++)
            bfr[ni] = *(const ushort8*)(Ws + (wn * 64 + ni * 16 + (lane & 15)) * 32 + (lane >> 4) * 8);
#pragma unroll
        for (int mi = 0; mi < 4; mi++)
#pragma unroll
            for (int ni = 0; ni < 4; ni++)
                acc[mi][ni] = mfma16(af[mi], bfr[ni], acc[mi][ni]);
        __syncthreads();   // all fragment reads done before next-iter overwrite
    }
    // epilogue: D(row,col): row = quad*4+reg, col = lane&15 (m89-verified layout)
    const int cb = n0 + wn * 64 + (lane & 15);
    const int rb = m0 + wm * 64 + ((lane >> 4) * 4);
#pragma unroll
    for (int ni = 0; ni < 4; ni++) {
        int col = cb + ni * 16;
        float bv = bias ? bias[col] : 0.f;
#pragma unroll
        for (int mi = 0; mi < 4; mi++) {
#pragma unroll
            for (int rg = 0; rg < 4; rg++) {
                int row = rb + mi * 16 + rg;
                if (row >= M) continue;
                float t = acc[mi][ni][rg] + bv;
                if (ACT) t = 0.5f * t * (1.f + erff(t * 0.70710678118654752f));
                if (res) t += res[(size_t)row * Nc + col];
                if (OUTBF) ((u16*)Cv)[(size_t)row * Nc + col] = f2b(t);
                else       ((float*)Cv)[(size_t)row * Nc + col] = t;
            }
        }
    }
}

// ---------------- fused MFMA attention.
// qkv bf16 [M,2304] (q|k|v); rpt f32 [NRD,12]; O bf16 [M,768].
// grid (384, 4): block = (b,h) x 64 q-rows. 4 waves, wave w owns rows
// iw = y*64 + w*16 .. +15 (16x16x32 MFMA tiles). N padded to 224 (14 col
// tiles / 7 PV k-steps).
// LDS: Ks [224][72] bf16 (stride-72 -> conflict-free b128 B-frag reads),
//      Vt [64][256] bf16 XOR-swizzled (j ^= ((d&7)^((d>>3)&7))<<3) so both
//      the scalar transpose writes and the b128 B-frag reads are bank-free.
// Ps [64][232] ALIASES Ks (dead after the QK^T barrier) -> 63.5 KB total,
// 2 blocks/CU.
__device__ __forceinline__ int vswz(int d) {
    return ((d & 7) ^ ((d >> 3) & 7)) << 3;
}

__launch_bounds__(256)
__global__ void attn3_k(const u16* __restrict__ qkv, const float* __restrict__ rpt,
                        u16* __restrict__ O) {
    __shared__ u16 smem[16128 + 16384];          // 63.5 KB
    u16* Ks = smem;                              // [224][72]
    u16* Vt = smem + 16128;                      // [64][256] swizzled
    u16* Ps = smem;                              // [64][232], aliases Ks
    const int b = blockIdx.x / HEADS_, hh = blockIdx.x % HEADS_;
    const int i0 = blockIdx.y * 64;
    const int t = threadIdx.x;
    const int w = t >> 6, lane = t & 63;
    const int lhi = lane >> 4, llo = lane & 15;
    const size_t base = (size_t)b * N_ * QKV_ + (size_t)hh * HD_;
    const int iw = i0 + w * 16;

    // Q A-fragments straight from global (A[m=llo][k=lhi*8+e], kk=0,1)
    int qrow = iw + llo; if (qrow > 196) qrow = 196;
    const ushort8 af0 = *(const ushort8*)(qkv + base + (size_t)qrow * QKV_ + lhi * 8);
    const ushort8 af1 = *(const ushort8*)(qkv + base + (size_t)qrow * QKV_ + 32 + lhi * 8);

    // stage K rows + swizzled V^T
    for (int g = t; g < 1576; g += 256) {
        int j = g >> 3, d0 = (g & 7) * 8;
        ushort8 kv = *(const ushort8*)(qkv + base + (size_t)j * QKV_ + 768 + d0);
        *(ushort8*)(Ks + j * 72 + d0) = kv;
        ushort8 vv = *(const ushort8*)(qkv + base + (size_t)j * QKV_ + 1536 + d0);
#pragma unroll
        for (int e = 0; e < 8; e++) {
            int d = d0 + e;
            Vt[d * 256 + (j ^ vswz(d))] = ((const u16*)&vv)[e];
        }
    }
    // zero pads: Ks rows 197..223, Vt logical cols 197..223
    if (t < 216) {
        int j = 197 + (t >> 3), d0 = (t & 7) * 8;
        *(uint4*)(Ks + j * 72 + d0) = make_uint4(0u, 0u, 0u, 0u);
    }
    for (int g = t; g < 1728; g += 256) {
        int d = g / 27, c = 197 + (g - d * 27);
        Vt[d * 256 + (c ^ vswz(d))] = 0;
    }
    __syncthreads();

    const bool wvalid = (iw <= 196);
    f32x4 acc[14] = {};
    float mx[4], sum[4];

    if (wvalid) {
        // ---- QK^T: S[iw+0..15][0..223]
#pragma unroll
        for (int jt = 0; jt < 14; jt++) {
            const u16* kp = Ks + (jt * 16 + llo) * 72 + lhi * 8;
            ushort8 b0 = *(const ushort8*)(kp);
            ushort8 b1 = *(const ushort8*)(kp + 32);
            acc[jt] = mfma16(af0, b0, acc[jt]);
            acc[jt] = mfma16(af1, b1, acc[jt]);
        }
        // ---- bias + mask + row max (rows live in 16 lanes differing in bits 0-3)
        int iy4[4], ix4[4]; bool icls[4];
#pragma unroll
        for (int rg = 0; rg < 4; rg++) {
            int i = iw + lhi * 4 + rg; if (i > 196) i = 196;
            icls[rg] = (i == 0);
            int pi = i - 1;
            iy4[rg] = pi / 14; ix4[rg] = pi - iy4[rg] * 14;
            mx[rg] = -INFINITY;
        }
#pragma unroll
        for (int jt = 0; jt < 14; jt++) {
            int j = jt * 16 + llo;
            if (j <= 196) {
                bool jcls = (j == 0);
                int pj = j - 1;
                int jy = pj / 14, jx = pj - jy * 14;
#pragma unroll
                for (int rg = 0; rg < 4; rg++) {
                    int idx;
                    if (icls[rg])  idx = jcls ? (NRD_ - 1) : (NRD_ - 3);
                    else if (jcls) idx = NRD_ - 2;
                    else           idx = (iy4[rg] - jy + 13) * 27 + (ix4[rg] - jx + 13);
                    float sv = acc[jt][rg] * 0.125f + rpt[idx * HEADS_ + hh];
                    acc[jt][rg] = sv;
                    mx[rg] = fmaxf(mx[rg], sv);
                }
            } else {
#pragma unroll
                for (int rg = 0; rg < 4; rg++) acc[jt][rg] = -INFINITY;
            }
        }
#pragma unroll
        for (int rg = 0; rg < 4; rg++) {
#pragma unroll
            for (int off = 1; off < 16; off <<= 1)
                mx[rg] = fmaxf(mx[rg], __shfl_xor(mx[rg], off, 64));
            sum[rg] = 0.f;
        }
        // ---- exp + row sum + normalize (in registers)
#pragma unroll
        for (int jt = 0; jt < 14; jt++)
#pragma unroll
            for (int rg = 0; rg < 4; rg++) {
                float ev = __expf(acc[jt][rg] - mx[rg]);
                acc[jt][rg] = ev;
                sum[rg] += ev;
            }
#pragma unroll
        for (int rg = 0; rg < 4; rg++) {
#pragma unroll
            for (int off = 1; off < 16; off <<= 1)
                sum[rg] += __shfl_xor(sum[rg], off, 64);
            sum[rg] = 1.f / sum[rg];
        }
#pragma unroll
        for (int jt = 0; jt < 14; jt++)
#pragma unroll
            for (int rg = 0; rg < 4; rg++) acc[jt][rg] *= sum[rg];
    }
    __syncthreads();   // all Ks reads done -> Ps may overwrite

    if (wvalid) {
        // ---- write P (bf16) to own 16 rows of Ps
#pragma unroll
        for (int jt = 0; jt < 14; jt++)
#pragma unroll
            for (int rg = 0; rg < 4; rg++)
                Ps[(w * 16 + lhi * 4 + rg) * 232 + jt * 16 + llo] = f2b(acc[jt][rg]);
        // ---- PV: O[16 x 64] = P[16 x 224] @ V[224 x 64]
        f32x4 o[4] = {};
#pragma unroll
        for (int jk = 0; jk < 7; jk++) {
            ushort8 pa = *(const ushort8*)(Ps + (w * 16 + llo) * 232 + jk * 32 + lhi * 8);
#pragma unroll
            for (int dt = 0; dt < 4; dt++) {
                int d = dt * 16 + llo;
                ushort8 vf = *(const ushort8*)(Vt + d * 256 + ((jk * 32 + lhi * 8) ^ vswz(d)));
                o[dt] = mfma16(pa, vf, o[dt]);
            }
        }
        // ---- store (row = lhi*4+rg, col = dt*16+llo)
#pragma unroll
        for (int dt = 0; dt < 4; dt++)
#pragma unroll
            for (int rg = 0; rg < 4; rg++) {
                int i = iw + lhi * 4 + rg;
                if (i <= 196)
                    O[(size_t)(b * N_ + i) * DIM_ + hh * HD_ + dt * 16 + llo] = f2b(o[dt][rg]);
            }
    }
}

extern "C" void kernel_launch(void* const* d_in, const int* in_sizes, int n_in,
                              void* d_out, int out_size, void* d_ws, size_t ws_size,
                              hipStream_t stream) {
    (void)in_sizes; (void)n_in; (void)out_size; (void)ws_size;
    const float* x    = (const float*)d_in[0];
    const float* pew  = (const float*)d_in[1];
    const float* peb  = (const float*)d_in[2];
    const float* cls  = (const float*)d_in[3];
    const float* n1w  = (const float*)d_in[4];
    const float* n1b  = (const float*)d_in[5];
    const float* qkvw = (const float*)d_in[6];
    const float* qb   = (const float*)d_in[7];
    const float* vb   = (const float*)d_in[8];
    const float* rpt  = (const float*)d_in[9];
    const float* pw   = (const float*)d_in[10];
    const float* pb   = (const float*)d_in[11];
    const float* n2w  = (const float*)d_in[12];
    const float* n2b  = (const float*)d_in[13];
    const float* f1w  = (const float*)d_in[14];
    const float* f1b  = (const float*)d_in[15];
    const float* f2w  = (const float*)d_in[16];
    const float* f2b_ = (const float*)d_in[17];
    const float* nfw  = (const float*)d_in[18];
    const float* nfb  = (const float*)d_in[19];

    // workspace (floats): h | y(bf16) | un | wbuf(bf16) | qbias  ~= 82 MB
    float* ws = (float*)d_ws;
    float* h     = ws;                                   // 4,841,472 f32
    u16*   y     = (u16*)(ws + 4841472);                 // bf16 [M,768]
    float* un    = ws + 4841472 + 2420736;               // 9,682,944 f32 union
    u16*   wbuf  = (u16*)(un + 9682944);                 // 7,077,888 bf16
    float* qbias = (float*)(wbuf + 7077888);             // 2304 f32
    u16*   qkvb   = (u16*)un;                            // bf16 [M,2304]
    u16*   hidden = (u16*)un;                            // bf16 [M,3072]
    u16*   pmat   = (u16*)un;                            // bf16 [6272,768]
    float* pout   = un + 4816896;                        // f32  [6272,768]

    const int MT = (M_ + 127) / 128;  // 50

    // patch embed
    cvt_k<<<288, 256, 0, stream>>>(pew, wbuf, SEG1 / 8);
    patchify_k<<<(MP_ * DIM_ + 255) / 256, 256, 0, stream>>>(x, pmat);
    gemm_bt<0, 0><<<dim3(6, 49), 256, 0, stream>>>(pmat, wbuf, peb, nullptr, pout,
                                                   MP_, DIM_, DIM_);
    build_tokens_k<<<(M_ * DIM_ + 255) / 256, 256, 0, stream>>>(pout, cls, h);

    for (int l = 0; l < 12; l++) {
        layernorm_k<1><<<M_, 256, 0, stream>>>(h, n1w + l * DIM_, n1b + l * DIM_, y);
        cvt4_k<<<3456, 256, 0, stream>>>(qkvw + (size_t)l * SEG0, pw + (size_t)l * SEG1,
                                         f1w + (size_t)l * SEG2, f2w + (size_t)l * SEG3, wbuf);
        qkvbias_k<<<9, 256, 0, stream>>>(qb + l * DIM_, vb + l * DIM_, qbias);
        gemm_bt<0, 1><<<dim3(18, MT), 256, 0, stream>>>(y, wbuf, qbias, nullptr, qkvb,
                                                        M_, QKV_, DIM_);
        attn3_k<<<dim3(384, 4), 256, 0, stream>>>(qkvb, rpt + (size_t)l * NRD_ * HEADS_, y);
        gemm_bt<0, 0><<<dim3(6, MT), 256, 0, stream>>>(y, wbuf + SEG0, pb + l * DIM_, h, h,
                                                       M_, DIM_, DIM_);
        layernorm_k<1><<<M_, 256, 0, stream>>>(h, n2w + l * DIM_, n2b + l * DIM_, y);
        gemm_bt<1, 1><<<dim3(24, MT), 256, 0, stream>>>(y, wbuf + SEG0 + SEG1, f1b + l * FF_,
                                                        nullptr, hidden, M_, FF_, DIM_);
        gemm_bt<0, 0><<<dim3(6, MT), 256, 0, stream>>>(hidden, wbuf + SEG0 + SEG1 + SEG2,
                                                       f2b_ + l * DIM_, h, h, M_, DIM_, FF_);
    }
    layernorm_k<0><<<M_, 256, 0, stream>>>(h, nfw, nfb, d_out);
}

// Round 3
// 4365.083 us; speedup vs baseline: 1.4257x; 1.0250x over previous
//
#include <hip/hip_runtime.h>
#include <hip/hip_bf16.h>

// ViT-B/16 forward, MI355X. Round 5: GEMM double-buffered LDS pipeline
// (stage next K-tile before computing current, ONE barrier per K-step) +
// bijective XCD-aware block swizzle (m204). MFMA attention unchanged.
//
// B=32, IMG=224 -> 196 patches +cls = 197 tokens, DIM=768, HEADS=12, HD=64,
// FF=3072, DEPTH=12, NRD=732.

#define B_     32
#define DIM_   768
#define N_     197
#define M_     (B_*N_)      // 6304
#define NP_    196
#define MP_    (B_*NP_)     // 6272
#define HEADS_ 12
#define HD_    64
#define FF_    3072
#define NRD_   732
#define QKV_   2304

typedef unsigned short u16;
typedef unsigned int   u32;
typedef __attribute__((ext_vector_type(4))) float    f32x4;
typedef __attribute__((ext_vector_type(8))) u16      ushort8;
typedef __attribute__((ext_vector_type(8))) __bf16   bf16x8;

__device__ __forceinline__ float b2f(u16 u) {
    return __builtin_bit_cast(float, ((u32)u) << 16);
}
__device__ __forceinline__ u16 f2b(float f) {  // RNE f32->bf16
    u32 u = __builtin_bit_cast(u32, f);
    u32 r = u + 0x7fffu + ((u >> 16) & 1u);
    return (u16)(r >> 16);
}
__device__ __forceinline__ float lo16(u32 v) { return __builtin_bit_cast(float, v << 16); }
__device__ __forceinline__ float hi16(u32 v) { return __builtin_bit_cast(float, v & 0xffff0000u); }

__device__ __forceinline__ f32x4 mfma16(ushort8 a, ushort8 b, f32x4 c) {
    return __builtin_amdgcn_mfma_f32_16x16x32_bf16(
        __builtin_bit_cast(bf16x8, a), __builtin_bit_cast(bf16x8, b), c, 0, 0, 0);
}

// async 16B global->LDS copy: lds base must be wave-uniform; g is per-lane.
__device__ __forceinline__ void gload16(const u16* g, u16* lds) {
    __builtin_amdgcn_global_load_lds(
        (const __attribute__((address_space(1))) void*)g,
        (__attribute__((address_space(3))) void*)lds, 16, 0, 0);
}

// ---------------- f32 -> bf16 converters ----------------
__global__ void cvt_k(const float* __restrict__ src, u16* __restrict__ dst, int n8) {
    int g = blockIdx.x * 256 + threadIdx.x;
    if (g >= n8) return;
    size_t o = (size_t)g * 8;
    float4 f0 = *(const float4*)(src + o);
    float4 f1 = *(const float4*)(src + o + 4);
    ushort8 r;
    r[0]=f2b(f0.x); r[1]=f2b(f0.y); r[2]=f2b(f0.z); r[3]=f2b(f0.w);
    r[4]=f2b(f1.x); r[5]=f2b(f1.y); r[6]=f2b(f1.z); r[7]=f2b(f1.w);
    *(ushort8*)(dst + o) = r;
}

// one layer's 4 weight mats -> contiguous bf16 wbuf [qkv|proj|fc1|fc2]
#define SEG0 1769472   // 2304*768
#define SEG1 589824    // 768*768
#define SEG2 2359296   // 3072*768
#define SEG3 2359296   // 768*3072
__global__ void cvt4_k(const float* __restrict__ s0, const float* __restrict__ s1,
                       const float* __restrict__ s2, const float* __restrict__ s3,
                       u16* __restrict__ dst) {
    int g = blockIdx.x * 256 + threadIdx.x;
    if (g >= (SEG0+SEG1+SEG2+SEG3)/8) return;
    size_t o = (size_t)g * 8;
    const float* src; size_t lo_;
    if (o < SEG0)             { src = s0; lo_ = o; }
    else if (o < SEG0+SEG1)   { src = s1; lo_ = o - SEG0; }
    else if (o < (size_t)SEG0+SEG1+SEG2) { src = s2; lo_ = o - SEG0 - SEG1; }
    else                      { src = s3; lo_ = o - SEG0 - SEG1 - SEG2; }
    float4 f0 = *(const float4*)(src + lo_);
    float4 f1 = *(const float4*)(src + lo_ + 4);
    ushort8 r;
    r[0]=f2b(f0.x); r[1]=f2b(f0.y); r[2]=f2b(f0.z); r[3]=f2b(f0.w);
    r[4]=f2b(f1.x); r[5]=f2b(f1.y); r[6]=f2b(f1.z); r[7]=f2b(f1.w);
    *(ushort8*)(dst + o) = r;
}

// ---------------- patchify: x[B,3,224,224] -> P bf16 [6272,768]
__global__ void patchify_k(const float* __restrict__ X, u16* __restrict__ P) {
    int idx = blockIdx.x * 256 + threadIdx.x;
    if (idx >= MP_ * DIM_) return;
    int row = idx / DIM_, k = idx - row * DIM_;
    int b = row / NP_, p = row - b * NP_;
    int gy = p / 14, gx = p - gy * 14;
    int c = k >> 8, r = k & 255;
    int py = r >> 4, px = r & 15;
    P[idx] = f2b(X[((b * 3 + c) * 224 + gy * 16 + py) * 224 + gx * 16 + px]);
}

// ---------------- tokens: f32 patch-GEMM out + cls -> h f32
__global__ void build_tokens_k(const float* __restrict__ P, const float* __restrict__ cls,
                               float* __restrict__ T) {
    int idx = blockIdx.x * 256 + threadIdx.x;
    if (idx >= M_ * DIM_) return;
    int row = idx / DIM_, c = idx - row * DIM_;
    int b = row / N_, t = row - b * N_;
    T[idx] = (t == 0) ? cls[c] : P[(size_t)(b * NP_ + t - 1) * DIM_ + c];
}

// ---------------- qkv bias = concat(q_bias, 0, v_bias)  (f32)
__global__ void qkvbias_k(const float* __restrict__ qb, const float* __restrict__ vb,
                          float* __restrict__ out) {
    int n = blockIdx.x * 256 + threadIdx.x;
    if (n >= QKV_) return;
    out[n] = (n < DIM_) ? qb[n] : (n < 2 * DIM_ ? 0.f : vb[n - 2 * DIM_]);
}

// ---------------- LayerNorm (biased var, eps=1e-5). One block(256) per row.
template <int OUTBF>
__global__ void layernorm_k(const float* __restrict__ X, const float* __restrict__ w,
                            const float* __restrict__ bta, void* __restrict__ Yv) {
    int row = blockIdx.x;
    const float* x = X + (size_t)row * DIM_;
    int t = threadIdx.x;
    float v[3]; float s = 0.f, q = 0.f;
#pragma unroll
    for (int i = 0; i < 3; i++) { float u = x[t + i * 256]; v[i] = u; s += u; q += u * u; }
#pragma unroll
    for (int off = 32; off > 0; off >>= 1) {
        s += __shfl_down(s, off, 64);
        q += __shfl_down(q, off, 64);
    }
    __shared__ float ss[4], qq[4];
    int wid = t >> 6, lane = t & 63;
    if (!lane) { ss[wid] = s; qq[wid] = q; }
    __syncthreads();
    s = ss[0] + ss[1] + ss[2] + ss[3];
    q = qq[0] + qq[1] + qq[2] + qq[3];
    float mu = s * (1.f / 768.f);
    float var = q * (1.f / 768.f) - mu * mu;
    float rs = rsqrtf(var + 1e-5f);
#pragma unroll
    for (int i = 0; i < 3; i++) {
        int c = t + i * 256;
        float o = (v[i] - mu) * rs * w[c] + bta[c];
        if (OUTBF) ((u16*)Yv)[(size_t)row * DIM_ + c] = f2b(o);
        else       ((float*)Yv)[(size_t)row * DIM_ + c] = o;
    }
}

// ---------------- MFMA NT GEMM: C[M,Nc] = A[M,K](bf16) * W[Nc,K]^T(bf16)
// 128x128 tile, BK=32, 4 waves each 64x64 (4x4 of 16x16x32 mfma).
// Double-buffered LDS + global_load_lds width-16: issue next K-tile's async
// copies BEFORE computing current tile; single barrier per K-step (the
// compiler's vmcnt(0) drain before s_barrier lands AFTER compute, so the
// prefetch overlaps ds_read+MFMA). This targets the latency-bound regime of
// the small-grid dispatches (fc2/proj: 300 blocks on 256 CUs, ~1 wave/SIMD,
// zero TLP -> ILP is the only hiding mechanism).
// Bijective XCD swizzle (m204): blocks sharing an A row-panel land on the
// same XCD's L2 to cut cross-XCD panel re-fetch.
// Nc % 128 == 0; M edge clamped on load, masked on store.
template <int ACT, int OUTBF>   // ACT: erf-GELU; OUTBF: store bf16 else f32
__launch_bounds__(256)
__global__ void gemm_bt(const u16* __restrict__ A, const u16* __restrict__ W,
                        const float* __restrict__ bias, const float* res,
                        void* Cv, int M, int Nc, int K) {
    __shared__ u16 As[2][128 * 32];
    __shared__ u16 Ws[2][128 * 32];
    const int tid = threadIdx.x;
    const int lane = tid & 63, w = tid >> 6;
    const int wm = w & 1, wn = w >> 1;

    // bijective XCD-aware swizzle of the flat block id (m204)
    const int nwg = gridDim.x * gridDim.y;
    int bid = blockIdx.y * gridDim.x + blockIdx.x;
    {
        int q = nwg >> 3, r = nwg & 7;
        int xcd = bid & 7, idx = bid >> 3;
        bid = (xcd < r ? xcd * (q + 1) : r * (q + 1) + (xcd - r) * q) + idx;
    }
    const int m0 = (bid / gridDim.x) * 128, n0 = (bid % gridDim.x) * 128;

    f32x4 acc[4][4] = {};

    // per-lane global staging addresses (hoisted; +k0 per iter)
    const int srow = lane >> 2, scol = (lane & 3) * 8;
    int ar0 = m0 + w * 32 + srow;       if (ar0 >= M) ar0 = M - 1;
    int ar1 = m0 + w * 32 + 16 + srow;  if (ar1 >= M) ar1 = M - 1;
    const u16* ga0 = A + (size_t)ar0 * K + scol;
    const u16* ga1 = A + (size_t)ar1 * K + scol;
    const u16* gw0 = W + (size_t)(n0 + w * 32 + srow) * K + scol;
    const u16* gw1 = W + (size_t)(n0 + w * 32 + 16 + srow) * K + scol;
    const int lo0 = (w * 32) * 32, lo1 = (w * 32 + 16) * 32;  // wave-uniform LDS offs

    // prologue: stage tile 0 into buf 0
    gload16(ga0, As[0] + lo0);
    gload16(ga1, As[0] + lo1);
    gload16(gw0, Ws[0] + lo0);
    gload16(gw1, Ws[0] + lo1);
    __syncthreads();            // vmcnt(0) drain + barrier: tile 0 visible

    int cur = 0;
    for (int k0 = 32; k0 < K; k0 += 32) {
        // issue next tile's async copies first (overlap with compute below)
        const int nxt = cur ^ 1;
        gload16(ga0 + k0, As[nxt] + lo0);
        gload16(ga1 + k0, As[nxt] + lo1);
        gload16(gw0 + k0, Ws[nxt] + lo0);
        gload16(gw1 + k0, Ws[nxt] + lo1);
        // compute current tile
        ushort8 af[4], bfr[4];
#pragma unroll
        for (int mi = 0; mi < 4; mi++)
            af[mi] = *(const ushort8*)(As[cur] + (wm * 64 + mi * 16 + (lane & 15)) * 32 + (lane >> 4) * 8);
#pragma unroll
        for (int ni = 0; ni < 4; ni++)
            bfr[ni] = *(const ushort8*)(Ws[cur] + (wn * 64 + ni * 16 + (lane & 15)) * 32 + (lane >> 4) * 8);
#pragma unroll
        for (int mi = 0; mi < 4; mi++)
#pragma unroll
            for (int ni = 0; ni < 4; ni++)
                acc[mi][ni] = mfma16(af[mi], bfr[ni], acc[mi][ni]);
        __syncthreads();        // drains vmcnt (next tile staged) + guards buf reuse
        cur = nxt;
    }
    // epilogue tile (no prefetch)
    {
        ushort8 af[4], bfr[4];
#pragma unroll
        for (int mi = 0; mi < 4; mi++)
            af[mi] = *(const ushort8*)(As[cur] + (wm * 64 + mi * 16 + (lane & 15)) * 32 + (lane >> 4) * 8);
#pragma unroll
        for (int ni = 0; ni < 4; ni++)
            bfr[ni] = *(const ushort8*)(Ws[cur] + (wn * 64 + ni * 16 + (lane & 15)) * 32 + (lane >> 4) * 8);
#pragma unroll
        for (int mi = 0; mi < 4; mi++)
#pragma unroll
            for (int ni = 0; ni < 4; ni++)
                acc[mi][ni] = mfma16(af[mi], bfr[ni], acc[mi][ni]);
    }
    // epilogue: D(row,col): row = quad*4+reg, col = lane&15 (m89-verified layout)
    const int cb = n0 + wn * 64 + (lane & 15);
    const int rb = m0 + wm * 64 + ((lane >> 4) * 4);
#pragma unroll
    for (int ni = 0; ni < 4; ni++) {
        int col = cb + ni * 16;
        float bv = bias ? bias[col] : 0.f;
#pragma unroll
        for (int mi = 0; mi < 4; mi++) {
#pragma unroll
            for (int rg = 0; rg < 4; rg++) {
                int row = rb + mi * 16 + rg;
                if (row >= M) continue;
                float t = acc[mi][ni][rg] + bv;
                if (ACT) t = 0.5f * t * (1.f + erff(t * 0.70710678118654752f));
                if (res) t += res[(size_t)row * Nc + col];
                if (OUTBF) ((u16*)Cv)[(size_t)row * Nc + col] = f2b(t);
                else       ((float*)Cv)[(size_t)row * Nc + col] = t;
            }
        }
    }
}

// ---------------- fused MFMA attention.
// qkv bf16 [M,2304] (q|k|v); rpt f32 [NRD,12]; O bf16 [M,768].
// grid (384, 4): block = (b,h) x 64 q-rows. 4 waves, wave w owns rows
// iw = y*64 + w*16 .. +15 (16x16x32 MFMA tiles). N padded to 224 (14 col
// tiles / 7 PV k-steps).
// LDS: Ks [224][72] bf16 (stride-72 -> conflict-free b128 B-frag reads),
//      Vt [64][256] bf16 XOR-swizzled (j ^= ((d&7)^((d>>3)&7))<<3) so both
//      the scalar transpose writes and the b128 B-frag reads are bank-free.
// Ps [64][232] ALIASES Ks (dead after the QK^T barrier) -> 63.5 KB total,
// 2 blocks/CU.
__device__ __forceinline__ int vswz(int d) {
    return ((d & 7) ^ ((d >> 3) & 7)) << 3;
}

__launch_bounds__(256)
__global__ void attn3_k(const u16* __restrict__ qkv, const float* __restrict__ rpt,
                        u16* __restrict__ O) {
    __shared__ u16 smem[16128 + 16384];          // 63.5 KB
    u16* Ks = smem;                              // [224][72]
    u16* Vt = smem + 16128;                      // [64][256] swizzled
    u16* Ps = smem;                              // [64][232], aliases Ks
    const int b = blockIdx.x / HEADS_, hh = blockIdx.x % HEADS_;
    const int i0 = blockIdx.y * 64;
    const int t = threadIdx.x;
    const int w = t >> 6, lane = t & 63;
    const int lhi = lane >> 4, llo = lane & 15;
    const size_t base = (size_t)b * N_ * QKV_ + (size_t)hh * HD_;
    const int iw = i0 + w * 16;

    // Q A-fragments straight from global (A[m=llo][k=lhi*8+e], kk=0,1)
    int qrow = iw + llo; if (qrow > 196) qrow = 196;
    const ushort8 af0 = *(const ushort8*)(qkv + base + (size_t)qrow * QKV_ + lhi * 8);
    const ushort8 af1 = *(const ushort8*)(qkv + base + (size_t)qrow * QKV_ + 32 + lhi * 8);

    // stage K rows + swizzled V^T
    for (int g = t; g < 1576; g += 256) {
        int j = g >> 3, d0 = (g & 7) * 8;
        ushort8 kv = *(const ushort8*)(qkv + base + (size_t)j * QKV_ + 768 + d0);
        *(ushort8*)(Ks + j * 72 + d0) = kv;
        ushort8 vv = *(const ushort8*)(qkv + base + (size_t)j * QKV_ + 1536 + d0);
#pragma unroll
        for (int e = 0; e < 8; e++) {
            int d = d0 + e;
            Vt[d * 256 + (j ^ vswz(d))] = ((const u16*)&vv)[e];
        }
    }
    // zero pads: Ks rows 197..223, Vt logical cols 197..223
    if (t < 216) {
        int j = 197 + (t >> 3), d0 = (t & 7) * 8;
        *(uint4*)(Ks + j * 72 + d0) = make_uint4(0u, 0u, 0u, 0u);
    }
    for (int g = t; g < 1728; g += 256) {
        int d = g / 27, c = 197 + (g - d * 27);
        Vt[d * 256 + (c ^ vswz(d))] = 0;
    }
    __syncthreads();

    const bool wvalid = (iw <= 196);
    f32x4 acc[14] = {};
    float mx[4], sum[4];

    if (wvalid) {
        // ---- QK^T: S[iw+0..15][0..223]
#pragma unroll
        for (int jt = 0; jt < 14; jt++) {
            const u16* kp = Ks + (jt * 16 + llo) * 72 + lhi * 8;
            ushort8 b0 = *(const ushort8*)(kp);
            ushort8 b1 = *(const ushort8*)(kp + 32);
            acc[jt] = mfma16(af0, b0, acc[jt]);
            acc[jt] = mfma16(af1, b1, acc[jt]);
        }
        // ---- bias + mask + row max (rows live in 16 lanes differing in bits 0-3)
        int iy4[4], ix4[4]; bool icls[4];
#pragma unroll
        for (int rg = 0; rg < 4; rg++) {
            int i = iw + lhi * 4 + rg; if (i > 196) i = 196;
            icls[rg] = (i == 0);
            int pi = i - 1;
            iy4[rg] = pi / 14; ix4[rg] = pi - iy4[rg] * 14;
            mx[rg] = -INFINITY;
        }
#pragma unroll
        for (int jt = 0; jt < 14; jt++) {
            int j = jt * 16 + llo;
            if (j <= 196) {
                bool jcls = (j == 0);
                int pj = j - 1;
                int jy = pj / 14, jx = pj - jy * 14;
#pragma unroll
                for (int rg = 0; rg < 4; rg++) {
                    int idx;
                    if (icls[rg])  idx = jcls ? (NRD_ - 1) : (NRD_ - 3);
                    else if (jcls) idx = NRD_ - 2;
                    else           idx = (iy4[rg] - jy + 13) * 27 + (ix4[rg] - jx + 13);
                    float sv = acc[jt][rg] * 0.125f + rpt[idx * HEADS_ + hh];
                    acc[jt][rg] = sv;
                    mx[rg] = fmaxf(mx[rg], sv);
                }
            } else {
#pragma unroll
                for (int rg = 0; rg < 4; rg++) acc[jt][rg] = -INFINITY;
            }
        }
#pragma unroll
        for (int rg = 0; rg < 4; rg++) {
#pragma unroll
            for (int off = 1; off < 16; off <<= 1)
                mx[rg] = fmaxf(mx[rg], __shfl_xor(mx[rg], off, 64));
            sum[rg] = 0.f;
        }
        // ---- exp + row sum + normalize (in registers)
#pragma unroll
        for (int jt = 0; jt < 14; jt++)
#pragma unroll
            for (int rg = 0; rg < 4; rg++) {
                float ev = __expf(acc[jt][rg] - mx[rg]);
                acc[jt][rg] = ev;
                sum[rg] += ev;
            }
#pragma unroll
        for (int rg = 0; rg < 4; rg++) {
#pragma unroll
            for (int off = 1; off < 16; off <<= 1)
                sum[rg] += __shfl_xor(sum[rg], off, 64);
            sum[rg] = 1.f / sum[rg];
        }
#pragma unroll
        for (int jt = 0; jt < 14; jt++)
#pragma unroll
            for (int rg = 0; rg < 4; rg++) acc[jt][rg] *= sum[rg];
    }
    __syncthreads();   // all Ks reads done -> Ps may overwrite

    if (wvalid) {
        // ---- write P (bf16) to own 16 rows of Ps
#pragma unroll
        for (int jt = 0; jt < 14; jt++)
#pragma unroll
            for (int rg = 0; rg < 4; rg++)
                Ps[(w * 16 + lhi * 4 + rg) * 232 + jt * 16 + llo] = f2b(acc[jt][rg]);
        // ---- PV: O[16 x 64] = P[16 x 224] @ V[224 x 64]
        f32x4 o[4] = {};
#pragma unroll
        for (int jk = 0; jk < 7; jk++) {
            ushort8 pa = *(const ushort8*)(Ps + (w * 16 + llo) * 232 + jk * 32 + lhi * 8);
#pragma unroll
            for (int dt = 0; dt < 4; dt++) {
                int d = dt * 16 + llo;
                ushort8 vf = *(const ushort8*)(Vt + d * 256 + ((jk * 32 + lhi * 8) ^ vswz(d)));
                o[dt] = mfma16(pa, vf, o[dt]);
            }
        }
        // ---- store (row = lhi*4+rg, col = dt*16+llo)
#pragma unroll
        for (int dt = 0; dt < 4; dt++)
#pragma unroll
            for (int rg = 0; rg < 4; rg++) {
                int i = iw + lhi * 4 + rg;
                if (i <= 196)
                    O[(size_t)(b * N_ + i) * DIM_ + hh * HD_ + dt * 16 + llo] = f2b(o[dt][rg]);
            }
    }
}

extern "C" void kernel_launch(void* const* d_in, const int* in_sizes, int n_in,
                              void* d_out, int out_size, void* d_ws, size_t ws_size,
                              hipStream_t stream) {
    (void)in_sizes; (void)n_in; (void)out_size; (void)ws_size;
    const float* x    = (const float*)d_in[0];
    const float* pew  = (const float*)d_in[1];
    const float* peb  = (const float*)d_in[2];
    const float* cls  = (const float*)d_in[3];
    const float* n1w  = (const float*)d_in[4];
    const float* n1b  = (const float*)d_in[5];
    const float* qkvw = (const float*)d_in[6];
    const float* qb   = (const float*)d_in[7];
    const float* vb   = (const float*)d_in[8];
    const float* rpt  = (const float*)d_in[9];
    const float* pw   = (const float*)d_in[10];
    const float* pb   = (const float*)d_in[11];
    const float* n2w  = (const float*)d_in[12];
    const float* n2b  = (const float*)d_in[13];
    const float* f1w  = (const float*)d_in[14];
    const float* f1b  = (const float*)d_in[15];
    const float* f2w  = (const float*)d_in[16];
    const float* f2b_ = (const float*)d_in[17];
    const float* nfw  = (const float*)d_in[18];
    const float* nfb  = (const float*)d_in[19];

    // workspace (floats): h | y(bf16) | un | wbuf(bf16) | qbias  ~= 82 MB
    float* ws = (float*)d_ws;
    float* h     = ws;                                   // 4,841,472 f32
    u16*   y     = (u16*)(ws + 4841472);                 // bf16 [M,768]
    float* un    = ws + 4841472 + 2420736;               // 9,682,944 f32 union
    u16*   wbuf  = (u16*)(un + 9682944);                 // 7,077,888 bf16
    float* qbias = (float*)(wbuf + 7077888);             // 2304 f32
    u16*   qkvb   = (u16*)un;                            // bf16 [M,2304]
    u16*   hidden = (u16*)un;                            // bf16 [M,3072]
    u16*   pmat   = (u16*)un;                            // bf16 [6272,768]
    float* pout   = un + 4816896;                        // f32  [6272,768]

    const int MT = (M_ + 127) / 128;  // 50

    // patch embed
    cvt_k<<<288, 256, 0, stream>>>(pew, wbuf, SEG1 / 8);
    patchify_k<<<(MP_ * DIM_ + 255) / 256, 256, 0, stream>>>(x, pmat);
    gemm_bt<0, 0><<<dim3(6, 49), 256, 0, stream>>>(pmat, wbuf, peb, nullptr, pout,
                                                   MP_, DIM_, DIM_);
    build_tokens_k<<<(M_ * DIM_ + 255) / 256, 256, 0, stream>>>(pout, cls, h);

    for (int l = 0; l < 12; l++) {
        layernorm_k<1><<<M_, 256, 0, stream>>>(h, n1w + l * DIM_, n1b + l * DIM_, y);
        cvt4_k<<<3456, 256, 0, stream>>>(qkvw + (size_t)l * SEG0, pw + (size_t)l * SEG1,
                                         f1w + (size_t)l * SEG2, f2w + (size_t)l * SEG3, wbuf);
        qkvbias_k<<<9, 256, 0, stream>>>(qb + l * DIM_, vb + l * DIM_, qbias);
        gemm_bt<0, 1><<<dim3(18, MT), 256, 0, stream>>>(y, wbuf, qbias, nullptr, qkvb,
                                                        M_, QKV_, DIM_);
        attn3_k<<<dim3(384, 4), 256, 0, stream>>>(qkvb, rpt + (size_t)l * NRD_ * HEADS_, y);
        gemm_bt<0, 0><<<dim3(6, MT), 256, 0, stream>>>(y, wbuf + SEG0, pb + l * DIM_, h, h,
                                                       M_, DIM_, DIM_);
        layernorm_k<1><<<M_, 256, 0, stream>>>(h, n2w + l * DIM_, n2b + l * DIM_, y);
        gemm_bt<1, 1><<<dim3(24, MT), 256, 0, stream>>>(y, wbuf + SEG0 + SEG1, f1b + l * FF_,
                                                        nullptr, hidden, M_, FF_, DIM_);
        gemm_bt<0, 0><<<dim3(6, MT), 256, 0, stream>>>(hidden, wbuf + SEG0 + SEG1 + SEG2,
                                                       f2b_ + l * DIM_, h, h, M_, DIM_, FF_);
    }
    layernorm_k<0><<<M_, 256, 0, stream>>>(h, nfw, nfb, d_out);
}

// Round 4
// 3573.493 us; speedup vs baseline: 1.7416x; 1.2215x over previous
//
#include <hip/hip_runtime.h>
#include <hip/hip_bf16.h>

// ViT-B/16 forward, MI355X. Round 6: 8-wave (512-thread) GEMM blocks so each
// SIMD holds >=2 waves even at 1 block/CU (the fc2/proj small-grid regime was
// latency-bound at 1 wave/SIMD; m114 wave-level MFMA/VMEM co-scheduling needs
// a sibling wave). Same 128x128 tile, BK=32, double-buffered global_load_lds,
// bijective XCD swizzle. qkv bias precomputed for all layers in one launch.
// MFMA attention unchanged.
//
// B=32, IMG=224 -> 196 patches +cls = 197 tokens, DIM=768, HEADS=12, HD=64,
// FF=3072, DEPTH=12, NRD=732.

#define B_     32
#define DIM_   768
#define N_     197
#define M_     (B_*N_)      // 6304
#define NP_    196
#define MP_    (B_*NP_)     // 6272
#define HEADS_ 12
#define HD_    64
#define FF_    3072
#define NRD_   732
#define QKV_   2304
#define DEPTH_ 12

typedef unsigned short u16;
typedef unsigned int   u32;
typedef __attribute__((ext_vector_type(4))) float    f32x4;
typedef __attribute__((ext_vector_type(8))) u16      ushort8;
typedef __attribute__((ext_vector_type(8))) __bf16   bf16x8;

__device__ __forceinline__ float b2f(u16 u) {
    return __builtin_bit_cast(float, ((u32)u) << 16);
}
__device__ __forceinline__ u16 f2b(float f) {  // RNE f32->bf16
    u32 u = __builtin_bit_cast(u32, f);
    u32 r = u + 0x7fffu + ((u >> 16) & 1u);
    return (u16)(r >> 16);
}
__device__ __forceinline__ float lo16(u32 v) { return __builtin_bit_cast(float, v << 16); }
__device__ __forceinline__ float hi16(u32 v) { return __builtin_bit_cast(float, v & 0xffff0000u); }

__device__ __forceinline__ f32x4 mfma16(ushort8 a, ushort8 b, f32x4 c) {
    return __builtin_amdgcn_mfma_f32_16x16x32_bf16(
        __builtin_bit_cast(bf16x8, a), __builtin_bit_cast(bf16x8, b), c, 0, 0, 0);
}

// async 16B global->LDS copy: lds base must be wave-uniform; g is per-lane.
__device__ __forceinline__ void gload16(const u16* g, u16* lds) {
    __builtin_amdgcn_global_load_lds(
        (const __attribute__((address_space(1))) void*)g,
        (__attribute__((address_space(3))) void*)lds, 16, 0, 0);
}

// ---------------- f32 -> bf16 converters ----------------
__global__ void cvt_k(const float* __restrict__ src, u16* __restrict__ dst, int n8) {
    int g = blockIdx.x * 256 + threadIdx.x;
    if (g >= n8) return;
    size_t o = (size_t)g * 8;
    float4 f0 = *(const float4*)(src + o);
    float4 f1 = *(const float4*)(src + o + 4);
    ushort8 r;
    r[0]=f2b(f0.x); r[1]=f2b(f0.y); r[2]=f2b(f0.z); r[3]=f2b(f0.w);
    r[4]=f2b(f1.x); r[5]=f2b(f1.y); r[6]=f2b(f1.z); r[7]=f2b(f1.w);
    *(ushort8*)(dst + o) = r;
}

// one layer's 4 weight mats -> contiguous bf16 wbuf [qkv|proj|fc1|fc2]
#define SEG0 1769472   // 2304*768
#define SEG1 589824    // 768*768
#define SEG2 2359296   // 3072*768
#define SEG3 2359296   // 768*3072
__global__ void cvt4_k(const float* __restrict__ s0, const float* __restrict__ s1,
                       const float* __restrict__ s2, const float* __restrict__ s3,
                       u16* __restrict__ dst) {
    int g = blockIdx.x * 256 + threadIdx.x;
    if (g >= (SEG0+SEG1+SEG2+SEG3)/8) return;
    size_t o = (size_t)g * 8;
    const float* src; size_t lo_;
    if (o < SEG0)             { src = s0; lo_ = o; }
    else if (o < SEG0+SEG1)   { src = s1; lo_ = o - SEG0; }
    else if (o < (size_t)SEG0+SEG1+SEG2) { src = s2; lo_ = o - SEG0 - SEG1; }
    else                      { src = s3; lo_ = o - SEG0 - SEG1 - SEG2; }
    float4 f0 = *(const float4*)(src + lo_);
    float4 f1 = *(const float4*)(src + lo_ + 4);
    ushort8 r;
    r[0]=f2b(f0.x); r[1]=f2b(f0.y); r[2]=f2b(f0.z); r[3]=f2b(f0.w);
    r[4]=f2b(f1.x); r[5]=f2b(f1.y); r[6]=f2b(f1.z); r[7]=f2b(f1.w);
    *(ushort8*)(dst + o) = r;
}

// ---------------- patchify: x[B,3,224,224] -> P bf16 [6272,768]
__global__ void patchify_k(const float* __restrict__ X, u16* __restrict__ P) {
    int idx = blockIdx.x * 256 + threadIdx.x;
    if (idx >= MP_ * DIM_) return;
    int row = idx / DIM_, k = idx - row * DIM_;
    int b = row / NP_, p = row - b * NP_;
    int gy = p / 14, gx = p - gy * 14;
    int c = k >> 8, r = k & 255;
    int py = r >> 4, px = r & 15;
    P[idx] = f2b(X[((b * 3 + c) * 224 + gy * 16 + py) * 224 + gx * 16 + px]);
}

// ---------------- tokens: f32 patch-GEMM out + cls -> h f32
__global__ void build_tokens_k(const float* __restrict__ P, const float* __restrict__ cls,
                               float* __restrict__ T) {
    int idx = blockIdx.x * 256 + threadIdx.x;
    if (idx >= M_ * DIM_) return;
    int row = idx / DIM_, c = idx - row * DIM_;
    int b = row / N_, t = row - b * N_;
    T[idx] = (t == 0) ? cls[c] : P[(size_t)(b * NP_ + t - 1) * DIM_ + c];
}

// ---------------- qkv bias for ALL layers: concat(q_bias, 0, v_bias) per layer
__global__ void qkvbias_all_k(const float* __restrict__ qb, const float* __restrict__ vb,
                              float* __restrict__ out) {
    int g = blockIdx.x * 256 + threadIdx.x;
    if (g >= DEPTH_ * QKV_) return;
    int l = g / QKV_, n = g - l * QKV_;
    out[g] = (n < DIM_) ? qb[l * DIM_ + n]
                        : (n < 2 * DIM_ ? 0.f : vb[l * DIM_ + n - 2 * DIM_]);
}

// ---------------- LayerNorm (biased var, eps=1e-5). One block(256) per row.
template <int OUTBF>
__global__ void layernorm_k(const float* __restrict__ X, const float* __restrict__ w,
                            const float* __restrict__ bta, void* __restrict__ Yv) {
    int row = blockIdx.x;
    const float* x = X + (size_t)row * DIM_;
    int t = threadIdx.x;
    float v[3]; float s = 0.f, q = 0.f;
#pragma unroll
    for (int i = 0; i < 3; i++) { float u = x[t + i * 256]; v[i] = u; s += u; q += u * u; }
#pragma unroll
    for (int off = 32; off > 0; off >>= 1) {
        s += __shfl_down(s, off, 64);
        q += __shfl_down(q, off, 64);
    }
    __shared__ float ss[4], qq[4];
    int wid = t >> 6, lane = t & 63;
    if (!lane) { ss[wid] = s; qq[wid] = q; }
    __syncthreads();
    s = ss[0] + ss[1] + ss[2] + ss[3];
    q = qq[0] + qq[1] + qq[2] + qq[3];
    float mu = s * (1.f / 768.f);
    float var = q * (1.f / 768.f) - mu * mu;
    float rs = rsqrtf(var + 1e-5f);
#pragma unroll
    for (int i = 0; i < 3; i++) {
        int c = t + i * 256;
        float o = (v[i] - mu) * rs * w[c] + bta[c];
        if (OUTBF) ((u16*)Yv)[(size_t)row * DIM_ + c] = f2b(o);
        else       ((float*)Yv)[(size_t)row * DIM_ + c] = o;
    }
}

// ---------------- MFMA NT GEMM: C[M,Nc] = A[M,K](bf16) * W[Nc,K]^T(bf16)
// 128x128 tile, BK=32, 512 threads = 8 waves, each wave a 32x64 sub-tile
// (wm = w&3 -> M strip of 32, wn = w>>2 -> N strip of 64; acc[2][4]).
// Double-buffered LDS + global_load_lds width-16 (one call per array per wave
// per K-step: 512 lanes x 16B = the full 8KB tile). Prefetch next tile before
// computing current; single __syncthreads per K-step.
// Bijective XCD swizzle (m204). Nc % 128 == 0; M edge clamped, store masked.
template <int ACT, int OUTBF>   // ACT: erf-GELU; OUTBF: store bf16 else f32
__launch_bounds__(512)
__global__ void gemm_bt(const u16* __restrict__ A, const u16* __restrict__ W,
                        const float* __restrict__ bias, const float* res,
                        void* Cv, int M, int Nc, int K) {
    __shared__ u16 As[2][128 * 32];
    __shared__ u16 Ws[2][128 * 32];
    const int tid = threadIdx.x;
    const int lane = tid & 63, w = tid >> 6;
    const int llo = lane & 15, lhi = lane >> 4;
    const int wm = w & 3, wn = w >> 2;

    // bijective XCD-aware swizzle of the flat block id (m204)
    const int nwg = gridDim.x * gridDim.y;
    int bid = blockIdx.y * gridDim.x + blockIdx.x;
    {
        int q = nwg >> 3, r = nwg & 7;
        int xcd = bid & 7, idx = bid >> 3;
        bid = (xcd < r ? xcd * (q + 1) : r * (q + 1) + (xcd - r) * q) + idx;
    }
    const int m0 = (bid / gridDim.x) * 128, n0 = (bid % gridDim.x) * 128;

    f32x4 acc[2][4] = {};

    // staging: thread t covers row tid>>2 (0..127), 16B slot (tid&3).
    // wave w stages rows w*16..w*16+15 (1 KB region, lds addr = base + lane*16).
    const int srow = tid >> 2, scol = (tid & 3) * 8;
    int ar = m0 + srow; if (ar >= M) ar = M - 1;
    const u16* ga = A + (size_t)ar * K + scol;
    const u16* gw = W + (size_t)(n0 + srow) * K + scol;
    const int ldso = (w * 16) * 32;   // wave-uniform LDS offset

    // prologue: stage tile 0 into buf 0
    gload16(ga, As[0] + ldso);
    gload16(gw, Ws[0] + ldso);
    __syncthreads();            // vmcnt(0) drain + barrier: tile 0 visible

    int cur = 0;
    for (int k0 = 32; k0 < K; k0 += 32) {
        // issue next tile's async copies first (overlap with compute below)
        const int nxt = cur ^ 1;
        gload16(ga + k0, As[nxt] + ldso);
        gload16(gw + k0, Ws[nxt] + ldso);
        // compute current tile
        ushort8 af[2], bfr[4];
#pragma unroll
        for (int mi = 0; mi < 2; mi++)
            af[mi] = *(const ushort8*)(As[cur] + (wm * 32 + mi * 16 + llo) * 32 + lhi * 8);
#pragma unroll
        for (int ni = 0; ni < 4; ni++)
            bfr[ni] = *(const ushort8*)(Ws[cur] + (wn * 64 + ni * 16 + llo) * 32 + lhi * 8);
#pragma unroll
        for (int mi = 0; mi < 2; mi++)
#pragma unroll
            for (int ni = 0; ni < 4; ni++)
                acc[mi][ni] = mfma16(af[mi], bfr[ni], acc[mi][ni]);
        __syncthreads();        // drains vmcnt (next tile staged) + guards buf reuse
        cur = nxt;
    }
    // epilogue tile (no prefetch)
    {
        ushort8 af[2], bfr[4];
#pragma unroll
        for (int mi = 0; mi < 2; mi++)
            af[mi] = *(const ushort8*)(As[cur] + (wm * 32 + mi * 16 + llo) * 32 + lhi * 8);
#pragma unroll
        for (int ni = 0; ni < 4; ni++)
            bfr[ni] = *(const ushort8*)(Ws[cur] + (wn * 64 + ni * 16 + llo) * 32 + lhi * 8);
#pragma unroll
        for (int mi = 0; mi < 2; mi++)
#pragma unroll
            for (int ni = 0; ni < 4; ni++)
                acc[mi][ni] = mfma16(af[mi], bfr[ni], acc[mi][ni]);
    }
    // epilogue: D(row,col): row = quad*4+reg, col = lane&15 (m89-verified layout)
    const int cb = n0 + wn * 64 + llo;
    const int rb = m0 + wm * 32 + lhi * 4;
#pragma unroll
    for (int ni = 0; ni < 4; ni++) {
        int col = cb + ni * 16;
        float bv = bias ? bias[col] : 0.f;
#pragma unroll
        for (int mi = 0; mi < 2; mi++) {
#pragma unroll
            for (int rg = 0; rg < 4; rg++) {
                int row = rb + mi * 16 + rg;
                if (row >= M) continue;
                float t = acc[mi][ni][rg] + bv;
                if (ACT) t = 0.5f * t * (1.f + erff(t * 0.70710678118654752f));
                if (res) t += res[(size_t)row * Nc + col];
                if (OUTBF) ((u16*)Cv)[(size_t)row * Nc + col] = f2b(t);
                else       ((float*)Cv)[(size_t)row * Nc + col] = t;
            }
        }
    }
}

// ---------------- fused MFMA attention.
// qkv bf16 [M,2304] (q|k|v); rpt f32 [NRD,12]; O bf16 [M,768].
// grid (384, 4): block = (b,h) x 64 q-rows. 4 waves, wave w owns rows
// iw = y*64 + w*16 .. +15 (16x16x32 MFMA tiles). N padded to 224 (14 col
// tiles / 7 PV k-steps).
// LDS: Ks [224][72] bf16 (stride-72 -> conflict-free b128 B-frag reads),
//      Vt [64][256] bf16 XOR-swizzled (j ^= ((d&7)^((d>>3)&7))<<3) so both
//      the scalar transpose writes and the b128 B-frag reads are bank-free.
// Ps [64][232] ALIASES Ks (dead after the QK^T barrier) -> 63.5 KB total,
// 2 blocks/CU.
__device__ __forceinline__ int vswz(int d) {
    return ((d & 7) ^ ((d >> 3) & 7)) << 3;
}

__launch_bounds__(256)
__global__ void attn3_k(const u16* __restrict__ qkv, const float* __restrict__ rpt,
                        u16* __restrict__ O) {
    __shared__ u16 smem[16128 + 16384];          // 63.5 KB
    u16* Ks = smem;                              // [224][72]
    u16* Vt = smem + 16128;                      // [64][256] swizzled
    u16* Ps = smem;                              // [64][232], aliases Ks
    const int b = blockIdx.x / HEADS_, hh = blockIdx.x % HEADS_;
    const int i0 = blockIdx.y * 64;
    const int t = threadIdx.x;
    const int w = t >> 6, lane = t & 63;
    const int lhi = lane >> 4, llo = lane & 15;
    const size_t base = (size_t)b * N_ * QKV_ + (size_t)hh * HD_;
    const int iw = i0 + w * 16;

    // Q A-fragments straight from global (A[m=llo][k=lhi*8+e], kk=0,1)
    int qrow = iw + llo; if (qrow > 196) qrow = 196;
    const ushort8 af0 = *(const ushort8*)(qkv + base + (size_t)qrow * QKV_ + lhi * 8);
    const ushort8 af1 = *(const ushort8*)(qkv + base + (size_t)qrow * QKV_ + 32 + lhi * 8);

    // stage K rows + swizzled V^T
    for (int g = t; g < 1576; g += 256) {
        int j = g >> 3, d0 = (g & 7) * 8;
        ushort8 kv = *(const ushort8*)(qkv + base + (size_t)j * QKV_ + 768 + d0);
        *(ushort8*)(Ks + j * 72 + d0) = kv;
        ushort8 vv = *(const ushort8*)(qkv + base + (size_t)j * QKV_ + 1536 + d0);
#pragma unroll
        for (int e = 0; e < 8; e++) {
            int d = d0 + e;
            Vt[d * 256 + (j ^ vswz(d))] = ((const u16*)&vv)[e];
        }
    }
    // zero pads: Ks rows 197..223, Vt logical cols 197..223
    if (t < 216) {
        int j = 197 + (t >> 3), d0 = (t & 7) * 8;
        *(uint4*)(Ks + j * 72 + d0) = make_uint4(0u, 0u, 0u, 0u);
    }
    for (int g = t; g < 1728; g += 256) {
        int d = g / 27, c = 197 + (g - d * 27);
        Vt[d * 256 + (c ^ vswz(d))] = 0;
    }
    __syncthreads();

    const bool wvalid = (iw <= 196);
    f32x4 acc[14] = {};
    float mx[4], sum[4];

    if (wvalid) {
        // ---- QK^T: S[iw+0..15][0..223]
#pragma unroll
        for (int jt = 0; jt < 14; jt++) {
            const u16* kp = Ks + (jt * 16 + llo) * 72 + lhi * 8;
            ushort8 b0 = *(const ushort8*)(kp);
            ushort8 b1 = *(const ushort8*)(kp + 32);
            acc[jt] = mfma16(af0, b0, acc[jt]);
            acc[jt] = mfma16(af1, b1, acc[jt]);
        }
        // ---- bias + mask + row max (rows live in 16 lanes differing in bits 0-3)
        int iy4[4], ix4[4]; bool icls[4];
#pragma unroll
        for (int rg = 0; rg < 4; rg++) {
            int i = iw + lhi * 4 + rg; if (i > 196) i = 196;
            icls[rg] = (i == 0);
            int pi = i - 1;
            iy4[rg] = pi / 14; ix4[rg] = pi - iy4[rg] * 14;
            mx[rg] = -INFINITY;
        }
#pragma unroll
        for (int jt = 0; jt < 14; jt++) {
            int j = jt * 16 + llo;
            if (j <= 196) {
                bool jcls = (j == 0);
                int pj = j - 1;
                int jy = pj / 14, jx = pj - jy * 14;
#pragma unroll
                for (int rg = 0; rg < 4; rg++) {
                    int idx;
                    if (icls[rg])  idx = jcls ? (NRD_ - 1) : (NRD_ - 3);
                    else if (jcls) idx = NRD_ - 2;
                    else           idx = (iy4[rg] - jy + 13) * 27 + (ix4[rg] - jx + 13);
                    float sv = acc[jt][rg] * 0.125f + rpt[idx * HEADS_ + hh];
                    acc[jt][rg] = sv;
                    mx[rg] = fmaxf(mx[rg], sv);
                }
            } else {
#pragma unroll
                for (int rg = 0; rg < 4; rg++) acc[jt][rg] = -INFINITY;
            }
        }
#pragma unroll
        for (int rg = 0; rg < 4; rg++) {
#pragma unroll
            for (int off = 1; off < 16; off <<= 1)
                mx[rg] = fmaxf(mx[rg], __shfl_xor(mx[rg], off, 64));
            sum[rg] = 0.f;
        }
        // ---- exp + row sum + normalize (in registers)
#pragma unroll
        for (int jt = 0; jt < 14; jt++)
#pragma unroll
            for (int rg = 0; rg < 4; rg++) {
                float ev = __expf(acc[jt][rg] - mx[rg]);
                acc[jt][rg] = ev;
                sum[rg] += ev;
            }
#pragma unroll
        for (int rg = 0; rg < 4; rg++) {
#pragma unroll
            for (int off = 1; off < 16; off <<= 1)
                sum[rg] += __shfl_xor(sum[rg], off, 64);
            sum[rg] = 1.f / sum[rg];
        }
#pragma unroll
        for (int jt = 0; jt < 14; jt++)
#pragma unroll
            for (int rg = 0; rg < 4; rg++) acc[jt][rg] *= sum[rg];
    }
    __syncthreads();   // all Ks reads done -> Ps may overwrite

    if (wvalid) {
        // ---- write P (bf16) to own 16 rows of Ps
#pragma unroll
        for (int jt = 0; jt < 14; jt++)
#pragma unroll
            for (int rg = 0; rg < 4; rg++)
                Ps[(w * 16 + lhi * 4 + rg) * 232 + jt * 16 + llo] = f2b(acc[jt][rg]);
        // ---- PV: O[16 x 64] = P[16 x 224] @ V[224 x 64]
        f32x4 o[4] = {};
#pragma unroll
        for (int jk = 0; jk < 7; jk++) {
            ushort8 pa = *(const ushort8*)(Ps + (w * 16 + llo) * 232 + jk * 32 + lhi * 8);
#pragma unroll
            for (int dt = 0; dt < 4; dt++) {
                int d = dt * 16 + llo;
                ushort8 vf = *(const ushort8*)(Vt + d * 256 + ((jk * 32 + lhi * 8) ^ vswz(d)));
                o[dt] = mfma16(pa, vf, o[dt]);
            }
        }
        // ---- store (row = lhi*4+rg, col = dt*16+llo)
#pragma unroll
        for (int dt = 0; dt < 4; dt++)
#pragma unroll
            for (int rg = 0; rg < 4; rg++) {
                int i = iw + lhi * 4 + rg;
                if (i <= 196)
                    O[(size_t)(b * N_ + i) * DIM_ + hh * HD_ + dt * 16 + llo] = f2b(o[dt][rg]);
            }
    }
}

extern "C" void kernel_launch(void* const* d_in, const int* in_sizes, int n_in,
                              void* d_out, int out_size, void* d_ws, size_t ws_size,
                              hipStream_t stream) {
    (void)in_sizes; (void)n_in; (void)out_size; (void)ws_size;
    const float* x    = (const float*)d_in[0];
    const float* pew  = (const float*)d_in[1];
    const float* peb  = (const float*)d_in[2];
    const float* cls  = (const float*)d_in[3];
    const float* n1w  = (const float*)d_in[4];
    const float* n1b  = (const float*)d_in[5];
    const float* qkvw = (const float*)d_in[6];
    const float* qb   = (const float*)d_in[7];
    const float* vb   = (const float*)d_in[8];
    const float* rpt  = (const float*)d_in[9];
    const float* pw   = (const float*)d_in[10];
    const float* pb   = (const float*)d_in[11];
    const float* n2w  = (const float*)d_in[12];
    const float* n2b  = (const float*)d_in[13];
    const float* f1w  = (const float*)d_in[14];
    const float* f1b  = (const float*)d_in[15];
    const float* f2w  = (const float*)d_in[16];
    const float* f2b_ = (const float*)d_in[17];
    const float* nfw  = (const float*)d_in[18];
    const float* nfb  = (const float*)d_in[19];

    // workspace (floats): h | y(bf16) | un | wbuf(bf16) | qbias[12]  ~= 82 MB
    float* ws = (float*)d_ws;
    float* h     = ws;                                   // 4,841,472 f32
    u16*   y     = (u16*)(ws + 4841472);                 // bf16 [M,768]
    float* un    = ws + 4841472 + 2420736;               // 9,682,944 f32 union
    u16*   wbuf  = (u16*)(un + 9682944);                 // 7,077,888 bf16
    float* qbias = (float*)(wbuf + 7077888);             // 12*2304 f32
    u16*   qkvb   = (u16*)un;                            // bf16 [M,2304]
    u16*   hidden = (u16*)un;                            // bf16 [M,3072]
    u16*   pmat   = (u16*)un;                            // bf16 [6272,768]
    float* pout   = un + 4816896;                        // f32  [6272,768]

    const int MT = (M_ + 127) / 128;  // 50

    // patch embed
    cvt_k<<<288, 256, 0, stream>>>(pew, wbuf, SEG1 / 8);
    patchify_k<<<(MP_ * DIM_ + 255) / 256, 256, 0, stream>>>(x, pmat);
    qkvbias_all_k<<<(DEPTH_ * QKV_ + 255) / 256, 256, 0, stream>>>(qb, vb, qbias);
    gemm_bt<0, 0><<<dim3(6, 49), 512, 0, stream>>>(pmat, wbuf, peb, nullptr, pout,
                                                   MP_, DIM_, DIM_);
    build_tokens_k<<<(M_ * DIM_ + 255) / 256, 256, 0, stream>>>(pout, cls, h);

    for (int l = 0; l < 12; l++) {
        layernorm_k<1><<<M_, 256, 0, stream>>>(h, n1w + l * DIM_, n1b + l * DIM_, y);
        cvt4_k<<<3456, 256, 0, stream>>>(qkvw + (size_t)l * SEG0, pw + (size_t)l * SEG1,
                                         f1w + (size_t)l * SEG2, f2w + (size_t)l * SEG3, wbuf);
        gemm_bt<0, 1><<<dim3(18, MT), 512, 0, stream>>>(y, wbuf, qbias + l * QKV_, nullptr,
                                                        qkvb, M_, QKV_, DIM_);
        attn3_k<<<dim3(384, 4), 256, 0, stream>>>(qkvb, rpt + (size_t)l * NRD_ * HEADS_, y);
        gemm_bt<0, 0><<<dim3(6, MT), 512, 0, stream>>>(y, wbuf + SEG0, pb + l * DIM_, h, h,
                                                       M_, DIM_, DIM_);
        layernorm_k<1><<<M_, 256, 0, stream>>>(h, n2w + l * DIM_, n2b + l * DIM_, y);
        gemm_bt<1, 1><<<dim3(24, MT), 512, 0, stream>>>(y, wbuf + SEG0 + SEG1, f1b + l * FF_,
                                                        nullptr, hidden, M_, FF_, DIM_);
        gemm_bt<0, 0><<<dim3(6, MT), 512, 0, stream>>>(hidden, wbuf + SEG0 + SEG1 + SEG2,
                                                       f2b_ + l * DIM_, h, h, M_, DIM_, FF_);
    }
    layernorm_k<0><<<M_, 256, 0, stream>>>(h, nfw, nfb, d_out);
}

// Round 5
// 3446.545 us; speedup vs baseline: 1.8057x; 1.0368x over previous
//
#include <hip/hip_runtime.h>
#include <hip/hip_bf16.h>

// ViT-B/16 forward, MI355X. Round 7: counted-vmcnt GEMM pipeline (T4):
// 4-deep LDS buffers, stage tile t+3 after computing tile t, raw s_barrier
// (ONE per K-step), steady-state s_waitcnt vmcnt(4) -- prefetch stays in
// flight ACROSS the barrier (never drain to 0 in the main loop). Plus
// both-sides XOR slot swizzle on the staged tiles (global-source pre-swizzle
// + mirrored read XOR) to kill the 8-way ds_read_b128 bank conflict.
// 8 waves/512 threads, 128x128 tile, BK=32, bijective XCD swizzle.
// MFMA attention unchanged.
//
// B=32, IMG=224 -> 196 patches +cls = 197 tokens, DIM=768, HEADS=12, HD=64,
// FF=3072, DEPTH=12, NRD=732.

#define B_     32
#define DIM_   768
#define N_     197
#define M_     (B_*N_)      // 6304
#define NP_    196
#define MP_    (B_*NP_)     // 6272
#define HEADS_ 12
#define HD_    64
#define FF_    3072
#define NRD_   732
#define QKV_   2304
#define DEPTH_ 12

typedef unsigned short u16;
typedef unsigned int   u32;
typedef __attribute__((ext_vector_type(4))) float    f32x4;
typedef __attribute__((ext_vector_type(8))) u16      ushort8;
typedef __attribute__((ext_vector_type(8))) __bf16   bf16x8;

__device__ __forceinline__ float b2f(u16 u) {
    return __builtin_bit_cast(float, ((u32)u) << 16);
}
__device__ __forceinline__ u16 f2b(float f) {  // RNE f32->bf16
    u32 u = __builtin_bit_cast(u32, f);
    u32 r = u + 0x7fffu + ((u >> 16) & 1u);
    return (u16)(r >> 16);
}
__device__ __forceinline__ float lo16(u32 v) { return __builtin_bit_cast(float, v << 16); }
__device__ __forceinline__ float hi16(u32 v) { return __builtin_bit_cast(float, v & 0xffff0000u); }

__device__ __forceinline__ f32x4 mfma16(ushort8 a, ushort8 b, f32x4 c) {
    return __builtin_amdgcn_mfma_f32_16x16x32_bf16(
        __builtin_bit_cast(bf16x8, a), __builtin_bit_cast(bf16x8, b), c, 0, 0, 0);
}

// async 16B global->LDS copy: lds base must be wave-uniform; g is per-lane.
__device__ __forceinline__ void gload16(const u16* g, u16* lds) {
    __builtin_amdgcn_global_load_lds(
        (const __attribute__((address_space(1))) void*)g,
        (__attribute__((address_space(3))) void*)lds, 16, 0, 0);
}

// ---------------- f32 -> bf16 converters ----------------
__global__ void cvt_k(const float* __restrict__ src, u16* __restrict__ dst, int n8) {
    int g = blockIdx.x * 256 + threadIdx.x;
    if (g >= n8) return;
    size_t o = (size_t)g * 8;
    float4 f0 = *(const float4*)(src + o);
    float4 f1 = *(const float4*)(src + o + 4);
    ushort8 r;
    r[0]=f2b(f0.x); r[1]=f2b(f0.y); r[2]=f2b(f0.z); r[3]=f2b(f0.w);
    r[4]=f2b(f1.x); r[5]=f2b(f1.y); r[6]=f2b(f1.z); r[7]=f2b(f1.w);
    *(ushort8*)(dst + o) = r;
}

// one layer's 4 weight mats -> contiguous bf16 wbuf [qkv|proj|fc1|fc2]
#define SEG0 1769472   // 2304*768
#define SEG1 589824    // 768*768
#define SEG2 2359296   // 3072*768
#define SEG3 2359296   // 768*3072
__global__ void cvt4_k(const float* __restrict__ s0, const float* __restrict__ s1,
                       const float* __restrict__ s2, const float* __restrict__ s3,
                       u16* __restrict__ dst) {
    int g = blockIdx.x * 256 + threadIdx.x;
    if (g >= (SEG0+SEG1+SEG2+SEG3)/8) return;
    size_t o = (size_t)g * 8;
    const float* src; size_t lo_;
    if (o < SEG0)             { src = s0; lo_ = o; }
    else if (o < SEG0+SEG1)   { src = s1; lo_ = o - SEG0; }
    else if (o < (size_t)SEG0+SEG1+SEG2) { src = s2; lo_ = o - SEG0 - SEG1; }
    else                      { src = s3; lo_ = o - SEG0 - SEG1 - SEG2; }
    float4 f0 = *(const float4*)(src + lo_);
    float4 f1 = *(const float4*)(src + lo_ + 4);
    ushort8 r;
    r[0]=f2b(f0.x); r[1]=f2b(f0.y); r[2]=f2b(f0.z); r[3]=f2b(f0.w);
    r[4]=f2b(f1.x); r[5]=f2b(f1.y); r[6]=f2b(f1.z); r[7]=f2b(f1.w);
    *(ushort8*)(dst + o) = r;
}

// ---------------- patchify: x[B,3,224,224] -> P bf16 [6272,768]
__global__ void patchify_k(const float* __restrict__ X, u16* __restrict__ P) {
    int idx = blockIdx.x * 256 + threadIdx.x;
    if (idx >= MP_ * DIM_) return;
    int row = idx / DIM_, k = idx - row * DIM_;
    int b = row / NP_, p = row - b * NP_;
    int gy = p / 14, gx = p - gy * 14;
    int c = k >> 8, r = k & 255;
    int py = r >> 4, px = r & 15;
    P[idx] = f2b(X[((b * 3 + c) * 224 + gy * 16 + py) * 224 + gx * 16 + px]);
}

// ---------------- tokens: f32 patch-GEMM out + cls -> h f32
__global__ void build_tokens_k(const float* __restrict__ P, const float* __restrict__ cls,
                               float* __restrict__ T) {
    int idx = blockIdx.x * 256 + threadIdx.x;
    if (idx >= M_ * DIM_) return;
    int row = idx / DIM_, c = idx - row * DIM_;
    int b = row / N_, t = row - b * N_;
    T[idx] = (t == 0) ? cls[c] : P[(size_t)(b * NP_ + t - 1) * DIM_ + c];
}

// ---------------- qkv bias for ALL layers: concat(q_bias, 0, v_bias) per layer
__global__ void qkvbias_all_k(const float* __restrict__ qb, const float* __restrict__ vb,
                              float* __restrict__ out) {
    int g = blockIdx.x * 256 + threadIdx.x;
    if (g >= DEPTH_ * QKV_) return;
    int l = g / QKV_, n = g - l * QKV_;
    out[g] = (n < DIM_) ? qb[l * DIM_ + n]
                        : (n < 2 * DIM_ ? 0.f : vb[l * DIM_ + n - 2 * DIM_]);
}

// ---------------- LayerNorm (biased var, eps=1e-5). One block(256) per row.
template <int OUTBF>
__global__ void layernorm_k(const float* __restrict__ X, const float* __restrict__ w,
                            const float* __restrict__ bta, void* __restrict__ Yv) {
    int row = blockIdx.x;
    const float* x = X + (size_t)row * DIM_;
    int t = threadIdx.x;
    float v[3]; float s = 0.f, q = 0.f;
#pragma unroll
    for (int i = 0; i < 3; i++) { float u = x[t + i * 256]; v[i] = u; s += u; q += u * u; }
#pragma unroll
    for (int off = 32; off > 0; off >>= 1) {
        s += __shfl_down(s, off, 64);
        q += __shfl_down(q, off, 64);
    }
    __shared__ float ss[4], qq[4];
    int wid = t >> 6, lane = t & 63;
    if (!lane) { ss[wid] = s; qq[wid] = q; }
    __syncthreads();
    s = ss[0] + ss[1] + ss[2] + ss[3];
    q = qq[0] + qq[1] + qq[2] + qq[3];
    float mu = s * (1.f / 768.f);
    float var = q * (1.f / 768.f) - mu * mu;
    float rs = rsqrtf(var + 1e-5f);
#pragma unroll
    for (int i = 0; i < 3; i++) {
        int c = t + i * 256;
        float o = (v[i] - mu) * rs * w[c] + bta[c];
        if (OUTBF) ((u16*)Yv)[(size_t)row * DIM_ + c] = f2b(o);
        else       ((float*)Yv)[(size_t)row * DIM_ + c] = o;
    }
}

// ---------------- MFMA NT GEMM: C[M,Nc] = A[M,K](bf16) * W[Nc,K]^T(bf16)
// 128x128 tile, BK=32, 512 threads = 8 waves (wave = 32x64 sub-tile).
// Pipeline: 4 LDS buffers; stage tile t+3 after computing tile t; one raw
// s_barrier per K-step; steady-state s_waitcnt vmcnt(4) so 2 tiles of
// prefetch stay in flight across the barrier (T4 counted-vmcnt; drain only
// in the 2-step tail). Safety: a wave stages buf[(t+3)&3]=buf[(t-1)&3] only
// after passing barrier(t), which requires all waves to have finished
// compute(t-1) on that buffer.
// Bank conflicts: tile rows are 64B (4 x 16B slots). Physical slot s' of row
// r holds logical slot s = s' ^ ((r>>1)&3); global source picks the matching
// slot (LDS dest of global_load_lds stays linear, rule both-sides-or-neither),
// reads use the lane-constant mirror XOR -> 2 lanes/bank (free).
// Nc % 128 == 0; M edge clamped on load, masked on store.
template <int ACT, int OUTBF>   // ACT: erf-GELU; OUTBF: store bf16 else f32
__launch_bounds__(512)
__global__ void gemm_bt(const u16* __restrict__ A, const u16* __restrict__ W,
                        const float* __restrict__ bias, const float* res,
                        void* Cv, int M, int Nc, int K) {
    __shared__ u16 As[4][128 * 32];
    __shared__ u16 Ws[4][128 * 32];
    const int tid = threadIdx.x;
    const int lane = tid & 63, w = tid >> 6;
    const int llo = lane & 15, lhi = lane >> 4;
    const int wm = w & 3, wn = w >> 2;

    // bijective XCD-aware swizzle of the flat block id (m204)
    const int nwg = gridDim.x * gridDim.y;
    int bid = blockIdx.y * gridDim.x + blockIdx.x;
    {
        int q = nwg >> 3, r = nwg & 7;
        int xcd = bid & 7, idx = bid >> 3;
        bid = (xcd < r ? xcd * (q + 1) : r * (q + 1) + (xcd - r) * q) + idx;
    }
    const int m0 = (bid / gridDim.x) * 128, n0 = (bid % gridDim.x) * 128;

    f32x4 acc[2][4] = {};

    // staging: thread t -> physical (row tid>>2, slot tid&3); global source
    // fetches the LOGICAL slot that belongs there under the XOR swizzle.
    const int srow = tid >> 2;
    const int scol = ((tid & 3) ^ ((srow >> 1) & 3)) * 8;
    int ar = m0 + srow; if (ar >= M) ar = M - 1;
    const u16* ga = A + (size_t)ar * K + scol;
    const u16* gw = W + (size_t)(n0 + srow) * K + scol;
    const int ldso = (w * 16) * 32;   // wave-uniform LDS offset (1KB region)

    // read-side mirror XOR: row = base16 + llo (base16 multiple of 16) ->
    // (row>>1)&3 == (llo>>1)&3, lane-constant.
    const int rslot = (lhi ^ ((llo >> 1) & 3)) * 8;

    const int nt = K >> 5;   // BK=32 -> K/32 steps (>= 24 for all our shapes)

    // prologue: stage tiles 0..2 into bufs 0..2 (6 loads in flight)
#pragma unroll
    for (int p = 0; p < 3; ++p) {
        gload16(ga + p * 32, As[p] + ldso);
        gload16(gw + p * 32, Ws[p] + ldso);
    }

    for (int t = 0; t < nt; ++t) {
        // wait for tile t only; keep up to 2 newer tiles (4 loads) in flight
        if (t < nt - 2)      asm volatile("s_waitcnt vmcnt(4)" ::: "memory");
        else if (t < nt - 1) asm volatile("s_waitcnt vmcnt(2)" ::: "memory");
        else                 asm volatile("s_waitcnt vmcnt(0)" ::: "memory");
        __builtin_amdgcn_s_barrier();   // all waves' tile-t loads landed

        const u16* ab = As[t & 3];
        const u16* wb = Ws[t & 3];
        ushort8 af[2], bfr[4];
#pragma unroll
        for (int mi = 0; mi < 2; mi++)
            af[mi] = *(const ushort8*)(ab + (wm * 32 + mi * 16 + llo) * 32 + rslot);
#pragma unroll
        for (int ni = 0; ni < 4; ni++)
            bfr[ni] = *(const ushort8*)(wb + (wn * 64 + ni * 16 + llo) * 32 + rslot);
#pragma unroll
        for (int mi = 0; mi < 2; mi++)
#pragma unroll
            for (int ni = 0; ni < 4; ni++)
                acc[mi][ni] = mfma16(af[mi], bfr[ni], acc[mi][ni]);

        // stage tile t+3 into the buffer freed by compute(t-1)
        if (t + 3 < nt) {
            gload16(ga + (size_t)(t + 3) * 32, As[(t + 3) & 3] + ldso);
            gload16(gw + (size_t)(t + 3) * 32, Ws[(t + 3) & 3] + ldso);
        }
    }

    // epilogue: D(row,col): row = quad*4+reg, col = lane&15 (m89-verified layout)
    const int cb = n0 + wn * 64 + llo;
    const int rb = m0 + wm * 32 + lhi * 4;
#pragma unroll
    for (int ni = 0; ni < 4; ni++) {
        int col = cb + ni * 16;
        float bv = bias ? bias[col] : 0.f;
#pragma unroll
        for (int mi = 0; mi < 2; mi++) {
#pragma unroll
            for (int rg = 0; rg < 4; rg++) {
                int row = rb + mi * 16 + rg;
                if (row >= M) continue;
                float t = acc[mi][ni][rg] + bv;
                if (ACT) t = 0.5f * t * (1.f + erff(t * 0.70710678118654752f));
                if (res) t += res[(size_t)row * Nc + col];
                if (OUTBF) ((u16*)Cv)[(size_t)row * Nc + col] = f2b(t);
                else       ((float*)Cv)[(size_t)row * Nc + col] = t;
            }
        }
    }
}

// ---------------- fused MFMA attention.
// qkv bf16 [M,2304] (q|k|v); rpt f32 [NRD,12]; O bf16 [M,768].
// grid (384, 4): block = (b,h) x 64 q-rows. 4 waves, wave w owns rows
// iw = y*64 + w*16 .. +15 (16x16x32 MFMA tiles). N padded to 224 (14 col
// tiles / 7 PV k-steps).
// LDS: Ks [224][72] bf16 (stride-72 -> conflict-free b128 B-frag reads),
//      Vt [64][256] bf16 XOR-swizzled (j ^= ((d&7)^((d>>3)&7))<<3) so both
//      the scalar transpose writes and the b128 B-frag reads are bank-free.
// Ps [64][232] ALIASES Ks (dead after the QK^T barrier) -> 63.5 KB total,
// 2 blocks/CU.
__device__ __forceinline__ int vswz(int d) {
    return ((d & 7) ^ ((d >> 3) & 7)) << 3;
}

__launch_bounds__(256)
__global__ void attn3_k(const u16* __restrict__ qkv, const float* __restrict__ rpt,
                        u16* __restrict__ O) {
    __shared__ u16 smem[16128 + 16384];          // 63.5 KB
    u16* Ks = smem;                              // [224][72]
    u16* Vt = smem + 16128;                      // [64][256] swizzled
    u16* Ps = smem;                              // [64][232], aliases Ks
    const int b = blockIdx.x / HEADS_, hh = blockIdx.x % HEADS_;
    const int i0 = blockIdx.y * 64;
    const int t = threadIdx.x;
    const int w = t >> 6, lane = t & 63;
    const int lhi = lane >> 4, llo = lane & 15;
    const size_t base = (size_t)b * N_ * QKV_ + (size_t)hh * HD_;
    const int iw = i0 + w * 16;

    // Q A-fragments straight from global (A[m=llo][k=lhi*8+e], kk=0,1)
    int qrow = iw + llo; if (qrow > 196) qrow = 196;
    const ushort8 af0 = *(const ushort8*)(qkv + base + (size_t)qrow * QKV_ + lhi * 8);
    const ushort8 af1 = *(const ushort8*)(qkv + base + (size_t)qrow * QKV_ + 32 + lhi * 8);

    // stage K rows + swizzled V^T
    for (int g = t; g < 1576; g += 256) {
        int j = g >> 3, d0 = (g & 7) * 8;
        ushort8 kv = *(const ushort8*)(qkv + base + (size_t)j * QKV_ + 768 + d0);
        *(ushort8*)(Ks + j * 72 + d0) = kv;
        ushort8 vv = *(const ushort8*)(qkv + base + (size_t)j * QKV_ + 1536 + d0);
#pragma unroll
        for (int e = 0; e < 8; e++) {
            int d = d0 + e;
            Vt[d * 256 + (j ^ vswz(d))] = ((const u16*)&vv)[e];
        }
    }
    // zero pads: Ks rows 197..223, Vt logical cols 197..223
    if (t < 216) {
        int j = 197 + (t >> 3), d0 = (t & 7) * 8;
        *(uint4*)(Ks + j * 72 + d0) = make_uint4(0u, 0u, 0u, 0u);
    }
    for (int g = t; g < 1728; g += 256) {
        int d = g / 27, c = 197 + (g - d * 27);
        Vt[d * 256 + (c ^ vswz(d))] = 0;
    }
    __syncthreads();

    const bool wvalid = (iw <= 196);
    f32x4 acc[14] = {};
    float mx[4], sum[4];

    if (wvalid) {
        // ---- QK^T: S[iw+0..15][0..223]
#pragma unroll
        for (int jt = 0; jt < 14; jt++) {
            const u16* kp = Ks + (jt * 16 + llo) * 72 + lhi * 8;
            ushort8 b0 = *(const ushort8*)(kp);
            ushort8 b1 = *(const ushort8*)(kp + 32);
            acc[jt] = mfma16(af0, b0, acc[jt]);
            acc[jt] = mfma16(af1, b1, acc[jt]);
        }
        // ---- bias + mask + row max (rows live in 16 lanes differing in bits 0-3)
        int iy4[4], ix4[4]; bool icls[4];
#pragma unroll
        for (int rg = 0; rg < 4; rg++) {
            int i = iw + lhi * 4 + rg; if (i > 196) i = 196;
            icls[rg] = (i == 0);
            int pi = i - 1;
            iy4[rg] = pi / 14; ix4[rg] = pi - iy4[rg] * 14;
            mx[rg] = -INFINITY;
        }
#pragma unroll
        for (int jt = 0; jt < 14; jt++) {
            int j = jt * 16 + llo;
            if (j <= 196) {
                bool jcls = (j == 0);
                int pj = j - 1;
                int jy = pj / 14, jx = pj - jy * 14;
#pragma unroll
                for (int rg = 0; rg < 4; rg++) {
                    int idx;
                    if (icls[rg])  idx = jcls ? (NRD_ - 1) : (NRD_ - 3);
                    else if (jcls) idx = NRD_ - 2;
                    else           idx = (iy4[rg] - jy + 13) * 27 + (ix4[rg] - jx + 13);
                    float sv = acc[jt][rg] * 0.125f + rpt[idx * HEADS_ + hh];
                    acc[jt][rg] = sv;
                    mx[rg] = fmaxf(mx[rg], sv);
                }
            } else {
#pragma unroll
                for (int rg = 0; rg < 4; rg++) acc[jt][rg] = -INFINITY;
            }
        }
#pragma unroll
        for (int rg = 0; rg < 4; rg++) {
#pragma unroll
            for (int off = 1; off < 16; off <<= 1)
                mx[rg] = fmaxf(mx[rg], __shfl_xor(mx[rg], off, 64));
            sum[rg] = 0.f;
        }
        // ---- exp + row sum + normalize (in registers)
#pragma unroll
        for (int jt = 0; jt < 14; jt++)
#pragma unroll
            for (int rg = 0; rg < 4; rg++) {
                float ev = __expf(acc[jt][rg] - mx[rg]);
                acc[jt][rg] = ev;
                sum[rg] += ev;
            }
#pragma unroll
        for (int rg = 0; rg < 4; rg++) {
#pragma unroll
            for (int off = 1; off < 16; off <<= 1)
                sum[rg] += __shfl_xor(sum[rg], off, 64);
            sum[rg] = 1.f / sum[rg];
        }
#pragma unroll
        for (int jt = 0; jt < 14; jt++)
#pragma unroll
            for (int rg = 0; rg < 4; rg++) acc[jt][rg] *= sum[rg];
    }
    __syncthreads();   // all Ks reads done -> Ps may overwrite

    if (wvalid) {
        // ---- write P (bf16) to own 16 rows of Ps
#pragma unroll
        for (int jt = 0; jt < 14; jt++)
#pragma unroll
            for (int rg = 0; rg < 4; rg++)
                Ps[(w * 16 + lhi * 4 + rg) * 232 + jt * 16 + llo] = f2b(acc[jt][rg]);
        // ---- PV: O[16 x 64] = P[16 x 224] @ V[224 x 64]
        f32x4 o[4] = {};
#pragma unroll
        for (int jk = 0; jk < 7; jk++) {
            ushort8 pa = *(const ushort8*)(Ps + (w * 16 + llo) * 232 + jk * 32 + lhi * 8);
#pragma unroll
            for (int dt = 0; dt < 4; dt++) {
                int d = dt * 16 + llo;
                ushort8 vf = *(const ushort8*)(Vt + d * 256 + ((jk * 32 + lhi * 8) ^ vswz(d)));
                o[dt] = mfma16(pa, vf, o[dt]);
            }
        }
        // ---- store (row = lhi*4+rg, col = dt*16+llo)
#pragma unroll
        for (int dt = 0; dt < 4; dt++)
#pragma unroll
            for (int rg = 0; rg < 4; rg++) {
                int i = iw + lhi * 4 + rg;
                if (i <= 196)
                    O[(size_t)(b * N_ + i) * DIM_ + hh * HD_ + dt * 16 + llo] = f2b(o[dt][rg]);
            }
    }
}

extern "C" void kernel_launch(void* const* d_in, const int* in_sizes, int n_in,
                              void* d_out, int out_size, void* d_ws, size_t ws_size,
                              hipStream_t stream) {
    (void)in_sizes; (void)n_in; (void)out_size; (void)ws_size;
    const float* x    = (const float*)d_in[0];
    const float* pew  = (const float*)d_in[1];
    const float* peb  = (const float*)d_in[2];
    const float* cls  = (const float*)d_in[3];
    const float* n1w  = (const float*)d_in[4];
    const float* n1b  = (const float*)d_in[5];
    const float* qkvw = (const float*)d_in[6];
    const float* qb   = (const float*)d_in[7];
    const float* vb   = (const float*)d_in[8];
    const float* rpt  = (const float*)d_in[9];
    const float* pw   = (const float*)d_in[10];
    const float* pb   = (const float*)d_in[11];
    const float* n2w  = (const float*)d_in[12];
    const float* n2b  = (const float*)d_in[13];
    const float* f1w  = (const float*)d_in[14];
    const float* f1b  = (const float*)d_in[15];
    const float* f2w  = (const float*)d_in[16];
    const float* f2b_ = (const float*)d_in[17];
    const float* nfw  = (const float*)d_in[18];
    const float* nfb  = (const float*)d_in[19];

    // workspace (floats): h | y(bf16) | un | wbuf(bf16) | qbias[12]  ~= 82 MB
    float* ws = (float*)d_ws;
    float* h     = ws;                                   // 4,841,472 f32
    u16*   y     = (u16*)(ws + 4841472);                 // bf16 [M,768]
    float* un    = ws + 4841472 + 2420736;               // 9,682,944 f32 union
    u16*   wbuf  = (u16*)(un + 9682944);                 // 7,077,888 bf16
    float* qbias = (float*)(wbuf + 7077888);             // 12*2304 f32
    u16*   qkvb   = (u16*)un;                            // bf16 [M,2304]
    u16*   hidden = (u16*)un;                            // bf16 [M,3072]
    u16*   pmat   = (u16*)un;                            // bf16 [6272,768]
    float* pout   = un + 4816896;                        // f32  [6272,768]

    const int MT = (M_ + 127) / 128;  // 50

    // patch embed
    cvt_k<<<288, 256, 0, stream>>>(pew, wbuf, SEG1 / 8);
    patchify_k<<<(MP_ * DIM_ + 255) / 256, 256, 0, stream>>>(x, pmat);
    qkvbias_all_k<<<(DEPTH_ * QKV_ + 255) / 256, 256, 0, stream>>>(qb, vb, qbias);
    gemm_bt<0, 0><<<dim3(6, 49), 512, 0, stream>>>(pmat, wbuf, peb, nullptr, pout,
                                                   MP_, DIM_, DIM_);
    build_tokens_k<<<(M_ * DIM_ + 255) / 256, 256, 0, stream>>>(pout, cls, h);

    for (int l = 0; l < 12; l++) {
        layernorm_k<1><<<M_, 256, 0, stream>>>(h, n1w + l * DIM_, n1b + l * DIM_, y);
        cvt4_k<<<3456, 256, 0, stream>>>(qkvw + (size_t)l * SEG0, pw + (size_t)l * SEG1,
                                         f1w + (size_t)l * SEG2, f2w + (size_t)l * SEG3, wbuf);
        gemm_bt<0, 1><<<dim3(18, MT), 512, 0, stream>>>(y, wbuf, qbias + l * QKV_, nullptr,
                                                        qkvb, M_, QKV_, DIM_);
        attn3_k<<<dim3(384, 4), 256, 0, stream>>>(qkvb, rpt + (size_t)l * NRD_ * HEADS_, y);
        gemm_bt<0, 0><<<dim3(6, MT), 512, 0, stream>>>(y, wbuf + SEG0, pb + l * DIM_, h, h,
                                                       M_, DIM_, DIM_);
        layernorm_k<1><<<M_, 256, 0, stream>>>(h, n2w + l * DIM_, n2b + l * DIM_, y);
        gemm_bt<1, 1><<<dim3(24, MT), 512, 0, stream>>>(y, wbuf + SEG0 + SEG1, f1b + l * FF_,
                                                        nullptr, hidden, M_, FF_, DIM_);
        gemm_bt<0, 0><<<dim3(6, MT), 512, 0, stream>>>(hidden, wbuf + SEG0 + SEG1 + SEG2,
                                                       f2b_ + l * DIM_, h, h, M_, DIM_, FF_);
    }
    layernorm_k<0><<<M_, 256, 0, stream>>>(h, nfw, nfb, d_out);
}